// Round 21
// baseline (4022.420 us; speedup 1.0000x reference)
//
#include <hip/hip_runtime.h>
#include <cstddef>

#define B_   4096
#define L_   64
#define T_   256
#define H_   8
#define HD_  32
#define NL_  4
#define DFF_ 1024
#define DIN_ 6

typedef unsigned short ushort_t;
typedef __attribute__((ext_vector_type(8))) short bf16x8;
typedef __attribute__((ext_vector_type(4))) float f32x4;

// ---------------- helpers ----------------
__device__ __forceinline__ float wred_sum(float v) {
#pragma unroll
  for (int off = 32; off >= 1; off >>= 1) v += __shfl_xor(v, off, 64);
  return v;
}
__device__ __forceinline__ ushort_t f2bf(float f) {
  unsigned u = __builtin_bit_cast(unsigned, f);
  u += 0x7fffu + ((u >> 16) & 1u);  // RNE
  return (ushort_t)(u >> 16);
}
__device__ __forceinline__ float bf2f(ushort_t h) {
  unsigned u = ((unsigned)h) << 16;
  return __builtin_bit_cast(float, u);
}
// packed bf16 conversion: low16 = bf16(a), high16 = bf16(b). 1 VALU op.
__device__ __forceinline__ unsigned pk2bf(float a, float b) {
  unsigned r;
  asm volatile("v_cvt_pk_bf16_f32 %0, %1, %2" : "=v"(r) : "v"(a), "v"(b));
  return r;
}
__device__ __forceinline__ void gl16(const ushort_t* g, const ushort_t* l) {
  __builtin_amdgcn_global_load_lds(
      (const __attribute__((address_space(1))) unsigned int*)g,
      (__attribute__((address_space(3))) unsigned int*)l, 16, 0, 0);
}

// ---------------- input normalization (fp32), 4 batch elems/block ---------
__global__ __launch_bounds__(256) void normalize_k(const float* __restrict__ xs,
                                                   float* __restrict__ xn) {
  const int w = threadIdx.x >> 6;
  const int b = blockIdx.x * 4 + w;
  const int l = threadIdx.x & 63;
  const float* x = xs + ((size_t)b * L_ + l) * DIN_;
  const float x0 = x[0], x1 = x[1], x2 = x[2], x3 = x[3], x4 = x[4], x5 = x[5];
  const float prop = fmaxf(x0, 0.f), tx = fmaxf(x1, 0.f);
  const float sp = prop + tx;

  __shared__ float sh[4][64];
  __shared__ float med_sh[4];
  sh[w][l] = sp;
  __syncthreads();
  int rk = 0;
#pragma unroll 8
  for (int j = 0; j < 64; ++j) {
    const float vj = sh[w][j];
    rk += (vj < sp) || (vj == sp && j < l);
  }
  if (rk == 31) med_sh[w] = sp;
  __syncthreads();
  const float t_ref = fmaxf(med_sh[w], 1e-6f);

  float f[5];
  f[0] = prop / t_ref;
  f[1] = tx / t_ref;
  f[2] = x2;
  f[3] = log1pf(fmaxf(x3, 0.f));
  f[4] = log1pf(fmaxf(x4, 0.f) / t_ref);
  const float f5 = log1pf(fmaxf(x5, 0.f));

  float* dst = xn + ((size_t)b * L_ + l) * DIN_;
#pragma unroll
  for (int i = 0; i < 5; ++i) {
    float v = f[i];
    float m = wred_sum(v) * (1.f / 64.f);
    float d = v - m;
    float sd = sqrtf(wred_sum(d * d) * (1.f / 64.f)) + 1e-9f;
    const float lo = m - 3.f * sd, hi = m + 3.f * sd;
    const float cv = fminf(fmaxf(v, lo), hi);
    const float m2 = wred_sum(cv) * (1.f / 64.f);
    const float d2 = cv - m2;
    const float sd2 = sqrtf(wred_sum(d2 * d2) * (1.f / 64.f)) + 1e-9f;
    dst[i] = (cv - m2) / sd2;
  }
  dst[5] = f5;
}

// ---------------- positional encoding table ----------------
__global__ void pe_k(float* __restrict__ pe) {
  const int l = blockIdx.x;
  const int i = threadIdx.x;
  const float div = expf(-9.210340371976184f * (2.0f * i) / 256.0f);
  const float ang = (float)l * div;
  pe[l * T_ + 2 * i]     = sinf(ang);
  pe[l * T_ + 2 * i + 1] = cosf(ang);
}

// ---- weight -> MFMA B-fragment order, bf16 ----
__global__ void wfrag_k(const float* __restrict__ in, ushort_t* __restrict__ out,
                        int NK, int ksh) {
  const size_t z = blockIdx.z;
  const int idx = blockIdx.x * 256 + threadIdx.x;
  if (idx >= NK) return;
  const int e = idx & 7, li = (idx >> 3) & 15, t = idx >> 7;
  const int ks = t & ((1 << ksh) - 1), cb = t >> ksh;
  const int K = 8 << ksh;
  out[z * (size_t)NK + idx] =
      f2bf(in[z * (size_t)NK + (size_t)(cb * 16 + li) * K + ks * 8 + e]);
}

// link_W2 (L,T,T) -> bf16 transposed per-l: out[l][s][t] = in[l][t][s]
__global__ void w2t_k(const float* __restrict__ in, ushort_t* __restrict__ out) {
  const int idx = blockIdx.x * 256 + threadIdx.x;
  const int l = idx >> 16, r = idx & 65535, s = r >> 8, t = r & 255;
  out[idx] = f2bf(in[(l << 16) | (t << 8) | s]);
}

// ---------------- link MLP stage 1: 16 rows/block, coalesced ---------------
__global__ __launch_bounds__(256) void link1_k(const float* __restrict__ xn,
                                               const float* __restrict__ W1,
                                               const float* __restrict__ b1,
                                               ushort_t* __restrict__ h) {
  const size_t r0 = (size_t)blockIdx.x * 16;  // flat row = b*64 + l
  const int col = threadIdx.x;
#pragma unroll
  for (int i = 0; i < 16; ++i) {
    const size_t r = r0 + i;
    const int l = (int)(r & (L_ - 1));
    const float* x = xn + r * DIN_;
    float a = b1[l * T_ + col];
#pragma unroll
    for (int d = 0; d < DIN_; ++d)
      a = fmaf(x[d], W1[((size_t)l * DIN_ + d) * T_ + col], a);
    h[r * T_ + col] = f2bf(fmaxf(a, 0.f));
  }
}

// ---- link GEMM 128x256 tile, z = l, dbuf; epilogue bias+pe -> y32 only ----
__global__ __launch_bounds__(512) void linkgemm_k(
    const ushort_t* __restrict__ A,   // h at (b*64+l)*256 = b*16384 + l*256
    const ushort_t* __restrict__ W,   // W2T16 [l][256][256]
    const float* __restrict__ bias,   // link_b2 [l][256]
    const float* __restrict__ pe,     // [l][256]
    float* __restrict__ y32) {
  __shared__ ushort_t lA[2][4096];
  __shared__ ushort_t lB[2][8192];
  const int tid = threadIdx.x;
  const int lane = tid & 63, w = tid >> 6;
  const int wr = w >> 2, wc = w & 3;
  const size_t b0 = (size_t)blockIdx.x * 128;
  const int l = blockIdx.z;
  const ushort_t* Az = A + b0 * 16384 + (size_t)l * 256;
  const ushort_t* Wz = W + (size_t)l * 65536;

  const int sm = tid >> 6, sks = (tid >> 4) & 3, srr = tid & 15;

  auto stage = [&](int buf, int kt) {
    gl16(Az + (size_t)(16 * sm + srr) * 16384 + kt + sks * 8,
         &lA[buf][(tid & ~63) * 8]);
#pragma unroll
    for (int rd = 0; rd < 2; ++rd) {
      const int nb = sm + rd * 8;
      gl16(Wz + (size_t)(nb * 16 + srr) * 256 + kt + sks * 8,
           &lB[buf][rd * 4096 + (tid & ~63) * 8]);
    }
  };

  f32x4 acc[4][4];
#pragma unroll
  for (int mi = 0; mi < 4; ++mi)
#pragma unroll
    for (int ni = 0; ni < 4; ++ni) acc[mi][ni] = (f32x4){0.f, 0.f, 0.f, 0.f};

  stage(0, 0);
  asm volatile("s_waitcnt vmcnt(0)" ::: "memory");
  __syncthreads();
  int cur = 0;
  for (int t = 0; t < 8; ++t) {
    if (t + 1 < 8) stage(cur ^ 1, (t + 1) << 5);
    bf16x8 af[4], bfr[4];
#pragma unroll
    for (int mi = 0; mi < 4; ++mi)
      af[mi] = *(const bf16x8*)&lA[cur][((wr * 4 + mi) * 64 + lane) * 8];
#pragma unroll
    for (int ni = 0; ni < 4; ++ni)
      bfr[ni] = *(const bf16x8*)&lB[cur][((wc * 4 + ni) * 64 + lane) * 8];
#pragma unroll
    for (int mi = 0; mi < 4; ++mi)
#pragma unroll
      for (int ni = 0; ni < 4; ++ni)
        acc[mi][ni] = __builtin_amdgcn_mfma_f32_16x16x32_bf16(
            af[mi], bfr[ni], acc[mi][ni], 0, 0, 0);
    asm volatile("s_waitcnt vmcnt(0)" ::: "memory");
    __syncthreads();
    cur ^= 1;
  }

  const int r_in = (lane >> 4) * 4;
  const int c_in = lane & 15;
#pragma unroll
  for (int ni = 0; ni < 4; ++ni) {
    const int cg = wc * 64 + ni * 16 + c_in;
    const float bs = bias[l * 256 + cg] + pe[l * 256 + cg];
#pragma unroll
    for (int mi = 0; mi < 4; ++mi) {
#pragma unroll
      for (int rg = 0; rg < 4; ++rg) {
        const size_t bg = b0 + wr * 64 + mi * 16 + r_in + rg;
        y32[bg * 16384 + l * 256 + cg] = acc[mi][ni][rg] + bs;
      }
    }
  }
}

// ==== FULL LAYER: 512 threads / 8 waves, ONE HEAD PER WAVE ====
// LAST=1: skip y32 write, emit pooled[b] instead. LDS 72 KB -> 2 blk/CU
// (16 waves/CU). bufw reused V->Q->K (r13-verified ordering).
template <int LAST>
__global__ __launch_bounds__(512, 2) void layer_k(
    float* __restrict__ y32,
    const ushort_t* __restrict__ Wq, const float* __restrict__ bqkv,
    const ushort_t* __restrict__ Wo, const float* __restrict__ bo,
    const float* __restrict__ ln1g, const float* __restrict__ ln1b,
    const ushort_t* __restrict__ Wf1, const float* __restrict__ bf1,
    const ushort_t* __restrict__ Wf2, const float* __restrict__ bf2,
    const float* __restrict__ ln2g, const float* __restrict__ ln2b,
    float* __restrict__ pool) {
  __shared__ ushort_t yF[16384];     // 32 KB: y / O / y1 frag tile
  __shared__ ushort_t sc[18432];     // 36.9 KB: 8 x bufw(2304) | zF alias
  __shared__ float red[8][2][64];    // 4 KB
  const int b = blockIdx.x;
  const int tid = threadIdx.x, lane = tid & 63, w = tid >> 6;  // w in [0,8)
  const int li = lane & 15, g = lane >> 4;
  const size_t row0 = (size_t)b * 64;
  const float scale = 0.17677669529663687f;
  ushort_t* bufw = sc + w * 2304;   // V^T[32][72] / Q,K[64][36] / PT[32][72]
  ushort_t* zF   = sc;              // ff1 quarter tile (FF phase, 16384 u16)
  const int r_in = g * 4;
  const int c_in = li;
  const int hoff = w * 32;          // this wave's head

  // ---- stage: y32 -> bf16 frag tile (cvt_pk) ----
#pragma unroll
  for (int j = 0; j < 4; ++j) {
    const int u = j * 512 + tid;
    const int row = u & 63, ks = u >> 6;    // ks in 0..31
    const float* src = y32 + (row0 + row) * 256 + ks * 8;
    const float4 a = *(const float4*)src;
    const float4 c = *(const float4*)(src + 4);
    uint4 v;
    v.x = pk2bf(a.x, a.y);
    v.y = pk2bf(a.z, a.w);
    v.z = pk2bf(c.x, c.y);
    v.w = pk2bf(c.z, c.w);
    *(uint4*)&yF[(((row >> 4) * 32 + ks) * 16 + (row & 15)) * 8] = v;
  }
  __syncthreads();

  // ---- attention: this wave computes head w end-to-end ----
  f32x4 oa[4][2];
#pragma unroll
  for (int mi = 0; mi < 4; ++mi)
#pragma unroll
    for (int n2 = 0; n2 < 2; ++n2) oa[mi][n2] = (f32x4){0.f, 0.f, 0.f, 0.f};
  {
    f32x4 acc[3][2][4];
#pragma unroll
    for (int m = 0; m < 3; ++m)
#pragma unroll
      for (int n = 0; n < 2; ++n)
#pragma unroll
        for (int mi = 0; mi < 4; ++mi) acc[m][n][mi] = (f32x4){0.f, 0.f, 0.f, 0.f};
    __builtin_amdgcn_s_setprio(1);
#pragma unroll
    for (int kt = 0; kt < 8; ++kt) {
      bf16x8 af[4];
#pragma unroll
      for (int mi = 0; mi < 4; ++mi)
        af[mi] = *(const bf16x8*)&yF[((mi * 32 + kt * 4 + g) * 16 + li) * 8];
      bf16x8 bw[3][2];
#pragma unroll
      for (int m = 0; m < 3; ++m)
#pragma unroll
        for (int n = 0; n < 2; ++n)
          bw[m][n] = *(const bf16x8*)(Wq +
              (size_t)(((m * 16 + 2 * w + n) * 32 + kt * 4 + g) * 16 + li) * 8);
#pragma unroll
      for (int m = 0; m < 3; ++m)
#pragma unroll
        for (int n = 0; n < 2; ++n)
#pragma unroll
          for (int mi = 0; mi < 4; ++mi)
            acc[m][n][mi] = __builtin_amdgcn_mfma_f32_16x16x32_bf16(
                af[mi], bw[m][n], acc[m][n][mi], 0, 0, 0);
    }
    __builtin_amdgcn_s_setprio(0);
    float bs[3][2];
#pragma unroll
    for (int m = 0; m < 3; ++m)
#pragma unroll
      for (int n = 0; n < 2; ++n) bs[m][n] = bqkv[m * 256 + hoff + 16 * n + li];

    // V^T -> bufw [32][72] (uint2 store), read vb regs (V buffer then dead)
#pragma unroll
    for (int n = 0; n < 2; ++n)
#pragma unroll
      for (int mi = 0; mi < 4; ++mi) {
        const unsigned p0 = pk2bf(acc[2][n][mi][0] + bs[2][n],
                                  acc[2][n][mi][1] + bs[2][n]);
        const unsigned p1 = pk2bf(acc[2][n][mi][2] + bs[2][n],
                                  acc[2][n][mi][3] + bs[2][n]);
        *(uint2*)&bufw[(16 * n + li) * 72 + 16 * mi + 4 * g] = make_uint2(p0, p1);
      }
    bf16x8 vb[2][2];
#pragma unroll
    for (int ks = 0; ks < 2; ++ks)
#pragma unroll
      for (int n2 = 0; n2 < 2; ++n2)
        vb[ks][n2] = *(const bf16x8*)&bufw[(16 * n2 + li) * 72 + ks * 32 + g * 8];

    // Q -> bufw [64][36] (overwrite), read qb
#pragma unroll
    for (int n = 0; n < 2; ++n)
#pragma unroll
      for (int mi = 0; mi < 4; ++mi) {
        const unsigned p0 = pk2bf(acc[0][n][mi][0] + bs[0][n],
                                  acc[0][n][mi][1] + bs[0][n]);
        const unsigned p1 = pk2bf(acc[0][n][mi][2] + bs[0][n],
                                  acc[0][n][mi][3] + bs[0][n]);
        const int base = (16 * mi + 4 * g) * 36 + 16 * n + li;
        bufw[base]       = (ushort_t)p0;
        bufw[base + 36]  = (ushort_t)(p0 >> 16);
        bufw[base + 72]  = (ushort_t)p1;
        bufw[base + 108] = (ushort_t)(p1 >> 16);
      }
    bf16x8 qb[4];
#pragma unroll
    for (int ni = 0; ni < 4; ++ni)
      qb[ni] = *(const bf16x8*)&bufw[(16 * ni + li) * 36 + g * 8];

    // K -> bufw (overwrite), read ka
#pragma unroll
    for (int n = 0; n < 2; ++n)
#pragma unroll
      for (int mi = 0; mi < 4; ++mi) {
        const unsigned p0 = pk2bf(acc[1][n][mi][0] + bs[1][n],
                                  acc[1][n][mi][1] + bs[1][n]);
        const unsigned p1 = pk2bf(acc[1][n][mi][2] + bs[1][n],
                                  acc[1][n][mi][3] + bs[1][n]);
        const int base = (16 * mi + 4 * g) * 36 + 16 * n + li;
        bufw[base]       = (ushort_t)p0;
        bufw[base + 36]  = (ushort_t)(p0 >> 16);
        bufw[base + 72]  = (ushort_t)p1;
        bufw[base + 108] = (ushort_t)(p1 >> 16);
      }
    bf16x8 ka[4];
#pragma unroll
    for (int mi = 0; mi < 4; ++mi)
      ka[mi] = *(const bf16x8*)&bufw[(16 * mi + li) * 36 + g * 8];

#pragma unroll
    for (int half = 0; half < 2; ++half) {
      f32x4 s[4][2];
      __builtin_amdgcn_s_setprio(1);
#pragma unroll
      for (int mi = 0; mi < 4; ++mi)
#pragma unroll
        for (int nn = 0; nn < 2; ++nn)
          s[mi][nn] = __builtin_amdgcn_mfma_f32_16x16x32_bf16(
              ka[mi], qb[2 * half + nn], (f32x4){0.f, 0.f, 0.f, 0.f}, 0, 0, 0);
      __builtin_amdgcn_s_setprio(0);

#pragma unroll
      for (int nn = 0; nn < 2; ++nn) {
        float mx = -3.4e38f;
#pragma unroll
        for (int mi = 0; mi < 4; ++mi)
#pragma unroll
          for (int r = 0; r < 4; ++r) {
            s[mi][nn][r] *= scale;
            mx = fmaxf(mx, s[mi][nn][r]);
          }
        mx = fmaxf(mx, __shfl_xor(mx, 16, 64));
        mx = fmaxf(mx, __shfl_xor(mx, 32, 64));
        float sum = 0.f;
#pragma unroll
        for (int mi = 0; mi < 4; ++mi)
#pragma unroll
          for (int r = 0; r < 4; ++r) {
            const float e = expf(s[mi][nn][r] - mx);
            s[mi][nn][r] = e;
            sum += e;
          }
        sum += __shfl_xor(sum, 16, 64);
        sum += __shfl_xor(sum, 32, 64);
        const float inv = 1.f / sum;
        const int qrow = 16 * nn + li;
#pragma unroll
        for (int mi = 0; mi < 4; ++mi) {
          const unsigned lo = pk2bf(s[mi][nn][0] * inv, s[mi][nn][1] * inv);
          const unsigned hi2 = pk2bf(s[mi][nn][2] * inv, s[mi][nn][3] * inv);
          *(uint2*)&bufw[qrow * 72 + 16 * mi + 4 * g] = make_uint2(lo, hi2);
        }
      }

      __builtin_amdgcn_s_setprio(1);
#pragma unroll
      for (int ks = 0; ks < 2; ++ks) {
        bf16x8 pa[2];
#pragma unroll
        for (int m2 = 0; m2 < 2; ++m2)
          pa[m2] = *(const bf16x8*)&bufw[(16 * m2 + li) * 72 + ks * 32 + g * 8];
#pragma unroll
        for (int m2 = 0; m2 < 2; ++m2)
#pragma unroll
          for (int n2 = 0; n2 < 2; ++n2)
            oa[2 * half + m2][n2] = __builtin_amdgcn_mfma_f32_16x16x32_bf16(
                pa[m2], vb[ks][n2], oa[2 * half + m2][n2], 0, 0, 0);
      }
      __builtin_amdgcn_s_setprio(0);
    }
  }

  __syncthreads();  // all yF reads + sc use complete
  // O -> yF fragment order (head w's 32 cols)
#pragma unroll
  for (int mi = 0; mi < 4; ++mi)
#pragma unroll
    for (int n2 = 0; n2 < 2; ++n2) {
      const unsigned p0 = pk2bf(oa[mi][n2][0], oa[mi][n2][1]);
      const unsigned p1 = pk2bf(oa[mi][n2][2], oa[mi][n2][3]);
      const int col = hoff + 16 * n2 + li;
      const int base = ((mi * 32 + (col >> 3)) * 16 + 4 * g) * 8 + (col & 7);
      yF[base]      = (ushort_t)p0;
      yF[base + 8]  = (ushort_t)(p0 >> 16);
      yF[base + 16] = (ushort_t)p1;
      yF[base + 24] = (ushort_t)(p1 >> 16);
    }
  __syncthreads();

  // ---- Wo GEMM: wave w -> cols [32w, 32w+32), K=256 ----
  f32x4 accO[4][2];
#pragma unroll
  for (int mi = 0; mi < 4; ++mi)
#pragma unroll
    for (int ni = 0; ni < 2; ++ni) accO[mi][ni] = (f32x4){0.f, 0.f, 0.f, 0.f};
  __builtin_amdgcn_s_setprio(1);
#pragma unroll
  for (int kt = 0; kt < 8; ++kt) {
    bf16x8 af[4], bfr[2];
#pragma unroll
    for (int mi = 0; mi < 4; ++mi)
      af[mi] = *(const bf16x8*)&yF[((mi * 32 + kt * 4 + g) * 16 + li) * 8];
#pragma unroll
    for (int ni = 0; ni < 2; ++ni)
      bfr[ni] = *(const bf16x8*)(Wo +
          (size_t)(((2 * w + ni) * 32 + kt * 4 + g) * 16 + li) * 8);
#pragma unroll
    for (int mi = 0; mi < 4; ++mi)
#pragma unroll
      for (int ni = 0; ni < 2; ++ni)
        accO[mi][ni] = __builtin_amdgcn_mfma_f32_16x16x32_bf16(
            af[mi], bfr[ni], accO[mi][ni], 0, 0, 0);
  }
  __builtin_amdgcn_s_setprio(0);

  // ---- LN1: residual from y32, y1 -> registers (fp32) ----
  float y1r[4][2][4];
#pragma unroll
  for (int mi = 0; mi < 4; ++mi) {
#pragma unroll
    for (int rg = 0; rg < 4; ++rg) {
      const int row_l = 16 * mi + r_in + rg;
      float s1 = 0.f, s2 = 0.f;
#pragma unroll
      for (int ni = 0; ni < 2; ++ni) {
        const int cg = 32 * w + 16 * ni + c_in;
        const float zv = accO[mi][ni][rg] + bo[cg] + y32[(row0 + row_l) * 256 + cg];
        accO[mi][ni][rg] = zv;
        s1 += zv;
        s2 += zv * zv;
      }
#pragma unroll
      for (int off = 1; off <= 8; off <<= 1) {
        s1 += __shfl_xor(s1, off, 64);
        s2 += __shfl_xor(s2, off, 64);
      }
      if (c_in == 0) {
        red[w][0][row_l] = s1;
        red[w][1][row_l] = s2;
      }
    }
  }
  __syncthreads();  // also: all Wo yF reads complete
#pragma unroll
  for (int mi = 0; mi < 4; ++mi) {
#pragma unroll
    for (int rg = 0; rg < 4; ++rg) {
      const int row_l = 16 * mi + r_in + rg;
      float S1 = 0.f, S2 = 0.f;
#pragma unroll
      for (int ww = 0; ww < 8; ++ww) {
        S1 += red[ww][0][row_l];
        S2 += red[ww][1][row_l];
      }
      const float m = S1 * (1.f / 256.f);
      const float var = S2 * (1.f / 256.f) - m * m;
      const float rs = rsqrtf(var + 1e-5f);
      float tv[2];
#pragma unroll
      for (int ni = 0; ni < 2; ++ni) {
        const int cg = 32 * w + 16 * ni + c_in;
        tv[ni] = (accO[mi][ni][rg] - m) * rs * ln1g[cg] + ln1b[cg];
        y1r[mi][ni][rg] = tv[ni];
      }
      const unsigned p0 = pk2bf(tv[0], tv[1]);
#pragma unroll
      for (int ni = 0; ni < 2; ++ni) {
        const int cg = 32 * w + 16 * ni + c_in;
        const ushort_t hv = ni ? (ushort_t)(p0 >> 16) : (ushort_t)p0;
        yF[((mi * 32 + (cg >> 3)) * 16 + (row_l & 15)) * 8 + (cg & 7)] = hv;
      }
    }
  }
  __syncthreads();

  // ---- FF phase: 4 quarters; 8 waves cover the full 256 cols per pass ----
  f32x4 acc2[4][2];
#pragma unroll
  for (int mi = 0; mi < 4; ++mi)
#pragma unroll
    for (int ni = 0; ni < 2; ++ni) acc2[mi][ni] = (f32x4){0.f, 0.f, 0.f, 0.f};

#pragma unroll 1
  for (int q = 0; q < 4; ++q) {
    // ff1: cols [256q + 32w, +32)
    f32x4 acc1[4][2];
#pragma unroll
    for (int mi = 0; mi < 4; ++mi)
#pragma unroll
      for (int n = 0; n < 2; ++n) acc1[mi][n] = (f32x4){0.f, 0.f, 0.f, 0.f};
    __builtin_amdgcn_s_setprio(1);
#pragma unroll
    for (int kt = 0; kt < 8; ++kt) {
      bf16x8 af[4], bw[2];
#pragma unroll
      for (int mi = 0; mi < 4; ++mi)
        af[mi] = *(const bf16x8*)&yF[((mi * 32 + kt * 4 + g) * 16 + li) * 8];
#pragma unroll
      for (int n = 0; n < 2; ++n)
        bw[n] = *(const bf16x8*)(Wf1 +
            (size_t)(((16 * q + 2 * w + n) * 32 + kt * 4 + g) * 16 + li) * 8);
#pragma unroll
      for (int mi = 0; mi < 4; ++mi)
#pragma unroll
        for (int n = 0; n < 2; ++n)
          acc1[mi][n] = __builtin_amdgcn_mfma_f32_16x16x32_bf16(
              af[mi], bw[n], acc1[mi][n], 0, 0, 0);
    }
    __builtin_amdgcn_s_setprio(0);
    if (q) __syncthreads();  // prior quarter's zF reads complete
    // relu+bias -> zF frag order (kk = local col in quarter)
#pragma unroll
    for (int n = 0; n < 2; ++n) {
      const int kk = 32 * w + 16 * n + li;
      const float bb = bf1[256 * q + kk];
#pragma unroll
      for (int mi = 0; mi < 4; ++mi) {
        const unsigned p0 = pk2bf(fmaxf(acc1[mi][n][0] + bb, 0.f),
                                  fmaxf(acc1[mi][n][1] + bb, 0.f));
        const unsigned p1 = pk2bf(fmaxf(acc1[mi][n][2] + bb, 0.f),
                                  fmaxf(acc1[mi][n][3] + bb, 0.f));
        const int base = ((mi * 32 + (kk >> 3)) * 16 + 4 * g) * 8 + (kk & 7);
        zF[base]      = (ushort_t)p0;
        zF[base + 8]  = (ushort_t)(p0 >> 16);
        zF[base + 16] = (ushort_t)p1;
        zF[base + 24] = (ushort_t)(p1 >> 16);
      }
    }
    __syncthreads();
    // ff2 partial: K-slice [256q, +256), wave w -> out cols [32w, 32w+32)
    __builtin_amdgcn_s_setprio(1);
#pragma unroll
    for (int kt = 0; kt < 8; ++kt) {
      bf16x8 af2[4], bw2[2];
#pragma unroll
      for (int mi = 0; mi < 4; ++mi)
        af2[mi] = *(const bf16x8*)&zF[((mi * 32 + kt * 4 + g) * 16 + li) * 8];
#pragma unroll
      for (int ni = 0; ni < 2; ++ni)
        bw2[ni] = *(const bf16x8*)(Wf2 +
            (size_t)(((2 * w + ni) * 128 + 32 * q + kt * 4 + g) * 16 + li) * 8);
#pragma unroll
      for (int mi = 0; mi < 4; ++mi)
#pragma unroll
        for (int ni = 0; ni < 2; ++ni)
          acc2[mi][ni] = __builtin_amdgcn_mfma_f32_16x16x32_bf16(
              af2[mi], bw2[ni], acc2[mi][ni], 0, 0, 0);
    }
    __builtin_amdgcn_s_setprio(0);
  }

  // ---- LN2: residual = y1r (fp32 regs); write y32 or pooled ----
#pragma unroll
  for (int mi = 0; mi < 4; ++mi) {
#pragma unroll
    for (int rg = 0; rg < 4; ++rg) {
      const int row_l = 16 * mi + r_in + rg;
      float s1 = 0.f, s2 = 0.f;
#pragma unroll
      for (int ni = 0; ni < 2; ++ni) {
        const int cg = 32 * w + 16 * ni + c_in;
        const float zv = acc2[mi][ni][rg] + bf2[cg] + y1r[mi][ni][rg];
        acc2[mi][ni][rg] = zv;
        s1 += zv;
        s2 += zv * zv;
      }
#pragma unroll
      for (int off = 1; off <= 8; off <<= 1) {
        s1 += __shfl_xor(s1, off, 64);
        s2 += __shfl_xor(s2, off, 64);
      }
      if (c_in == 0) {
        red[w][0][row_l] = s1;
        red[w][1][row_l] = s2;
      }
    }
  }
  __syncthreads();
  float colsum[2] = {0.f, 0.f};
#pragma unroll
  for (int mi = 0; mi < 4; ++mi) {
#pragma unroll
    for (int rg = 0; rg < 4; ++rg) {
      const int row_l = 16 * mi + r_in + rg;
      float S1 = 0.f, S2 = 0.f;
#pragma unroll
      for (int ww = 0; ww < 8; ++ww) {
        S1 += red[ww][0][row_l];
        S2 += red[ww][1][row_l];
      }
      const float m = S1 * (1.f / 256.f);
      const float var = S2 * (1.f / 256.f) - m * m;
      const float rs = rsqrtf(var + 1e-5f);
#pragma unroll
      for (int ni = 0; ni < 2; ++ni) {
        const int cg = 32 * w + 16 * ni + c_in;
        const float v = (acc2[mi][ni][rg] - m) * rs * ln2g[cg] + ln2b[cg];
        if constexpr (LAST) {
          colsum[ni] += v;
        } else {
          y32[(row0 + row_l) * 256 + cg] = v;
        }
      }
    }
  }
  if constexpr (LAST) {
#pragma unroll
    for (int ni = 0; ni < 2; ++ni) {
      float s = colsum[ni];
      s += __shfl_xor(s, 16, 64);
      s += __shfl_xor(s, 32, 64);
      if (g == 0) pool[(size_t)b * 256 + 32 * w + 16 * ni + c_in] = s * (1.f / 64.f);
    }
  }
}

// ---------------- fp32 head GEMM (64-row tile, relu) ----------------
__global__ __launch_bounds__(256) void headgemm_k(
    const float* __restrict__ A, const float* __restrict__ Wt,
    const float* __restrict__ bias, float* __restrict__ out) {
  const int tid = threadIdx.x;
  const int tx = tid & 63, ty = tid >> 6;
  const int cfull = tx * 4;
  const size_t b0 = (size_t)blockIdx.x * 64;

  __shared__ float At[256][68];

  float4 acc[16];
#pragma unroll
  for (int r = 0; r < 16; ++r) acc[r] = make_float4(0.f, 0.f, 0.f, 0.f);
  const int r0 = ty * 16;

  {
    const int rr = tid >> 6;
    const int k4 = (tid & 63) * 4;
#pragma unroll
    for (int p = 0; p < 16; ++p) {
      const int r = p * 4 + rr;
      const float4 v = *(const float4*)(A + (b0 + r) * 256 + k4);
      At[k4 + 0][r] = v.x;
      At[k4 + 1][r] = v.y;
      At[k4 + 2][r] = v.z;
      At[k4 + 3][r] = v.w;
    }
  }
  __syncthreads();
  const float* wp = Wt + cfull;
#pragma unroll 2
  for (int k = 0; k < 256; ++k) {
    const float4 w = *(const float4*)wp;
    wp += 256;
    const float4* ar = (const float4*)(&At[k][r0]);
    const float4 a0 = ar[0], a1 = ar[1], a2 = ar[2], a3 = ar[3];
    const float av[16] = {a0.x, a0.y, a0.z, a0.w, a1.x, a1.y, a1.z, a1.w,
                          a2.x, a2.y, a2.z, a2.w, a3.x, a3.y, a3.z, a3.w};
#pragma unroll
    for (int r = 0; r < 16; ++r) {
      acc[r].x = fmaf(av[r], w.x, acc[r].x);
      acc[r].y = fmaf(av[r], w.y, acc[r].y);
      acc[r].z = fmaf(av[r], w.z, acc[r].z);
      acc[r].w = fmaf(av[r], w.w, acc[r].w);
    }
  }
  const float4 bb = *(const float4*)(bias + cfull);
#pragma unroll
  for (int r = 0; r < 16; ++r) {
    const size_t row = b0 + r0 + r;
    float4 o;
    o.x = fmaxf(acc[r].x + bb.x, 0.f);
    o.y = fmaxf(acc[r].y + bb.y, 0.f);
    o.z = fmaxf(acc[r].z + bb.z, 0.f);
    o.w = fmaxf(acc[r].w + bb.w, 0.f);
    *(float4*)(out + row * 256 + cfull) = o;
  }
}

__global__ __launch_bounds__(64) void head2_k(const float* __restrict__ hh,
                                              const float* __restrict__ W2,
                                              const float* __restrict__ b2,
                                              float* __restrict__ out) {
  const size_t b = blockIdx.x;
  const int lane = threadIdx.x;
  const float4 hv = *(const float4*)(hh + b * T_ + lane * 4);
  const float4 wv = *(const float4*)(W2 + lane * 4);
  float s = hv.x * wv.x + hv.y * wv.y + hv.z * wv.z + hv.w * wv.w;
  s = wred_sum(s);
  if (lane == 0) out[b] = s + b2[0];
}

// ---------------- launch ----------------
extern "C" void kernel_launch(void* const* d_in, const int* in_sizes, int n_in,
                              void* d_out, int out_size, void* d_ws, size_t ws_size,
                              hipStream_t stream) {
  const float* link_states = (const float*)d_in[0];
  const float* link_W1 = (const float*)d_in[1];
  const float* link_b1 = (const float*)d_in[2];
  const float* link_W2 = (const float*)d_in[3];
  const float* link_b2 = (const float*)d_in[4];
  const float* Wqkv = (const float*)d_in[5];
  const float* bqkv = (const float*)d_in[6];
  const float* Wo = (const float*)d_in[7];
  const float* bo = (const float*)d_in[8];
  const float* ln1_g = (const float*)d_in[9];
  const float* ln1_b = (const float*)d_in[10];
  const float* Wff1 = (const float*)d_in[11];
  const float* bff1 = (const float*)d_in[12];
  const float* Wff2 = (const float*)d_in[13];
  const float* bff2 = (const float*)d_in[14];
  const float* ln2_g = (const float*)d_in[15];
  const float* ln2_b = (const float*)d_in[16];
  const float* head_W1 = (const float*)d_in[17];
  const float* head_b1 = (const float*)d_in[18];
  const float* head_W2 = (const float*)d_in[19];
  const float* head_b2 = (const float*)d_in[20];

  char* base = (char*)d_ws;
  size_t off = 0;
  auto alloc = [&](size_t bytes) -> char* {
    char* p = base + off;
    off = (off + bytes + 255) & ~(size_t)255;
    return p;
  };

  // ---- fixed region (~29.4 MB) ----
  ushort_t* Wqkv16 = (ushort_t*)alloc((size_t)NL_ * 768 * 256 * 2);
  ushort_t* Wo16   = (ushort_t*)alloc((size_t)NL_ * 256 * 256 * 2);
  ushort_t* Wff116 = (ushort_t*)alloc((size_t)NL_ * 1024 * 256 * 2);
  ushort_t* Wff216 = (ushort_t*)alloc((size_t)NL_ * 256 * 1024 * 2);
  ushort_t* W2T16  = (ushort_t*)alloc((size_t)L_ * 256 * 256 * 2);
  float* pe     = (float*)alloc((size_t)L_ * T_ * 4);
  float* xn     = (float*)alloc((size_t)B_ * L_ * DIN_ * 4);
  float* pooled = (float*)alloc((size_t)B_ * T_ * 4);
  float* hh     = (float*)alloc((size_t)B_ * T_ * 4);

  // ---- chunked region: 98,304 B per batch element (y32 + hbuf) ----
  const size_t fixed_end = off;
  const size_t availB = (ws_size > fixed_end + 65536) ? (ws_size - fixed_end - 65536) : 0;
  int NC = 1;
  while (NC < 32 && (size_t)(B_ / NC) * 98304ull > availB) NC <<= 1;
  const int Bc = B_ / NC;

  float*    y32  = (float*)alloc((size_t)Bc * L_ * T_ * 4);
  ushort_t* hbuf = (ushort_t*)alloc((size_t)Bc * L_ * T_ * 2);

  // ---- prep: weights -> bf16 fragment order ----
  wfrag_k<<<dim3((768 * 256 + 255) / 256, 1, NL_), 256, 0, stream>>>(
      Wqkv, Wqkv16, 768 * 256, 5);
  wfrag_k<<<dim3((256 * 256 + 255) / 256, 1, NL_), 256, 0, stream>>>(
      Wo, Wo16, 256 * 256, 5);
  wfrag_k<<<dim3((1024 * 256 + 255) / 256, 1, NL_), 256, 0, stream>>>(
      Wff1, Wff116, 1024 * 256, 5);
  wfrag_k<<<dim3((256 * 1024 + 255) / 256, 1, NL_), 256, 0, stream>>>(
      Wff2, Wff216, 256 * 1024, 7);
  w2t_k<<<(L_ * 256 * 256) / 256, 256, 0, stream>>>(link_W2, W2T16);
  pe_k<<<L_, 128, 0, stream>>>(pe);
  normalize_k<<<B_ / 4, 256, 0, stream>>>(link_states, xn);

  for (int c = 0; c < NC; ++c) {
    const size_t bs = (size_t)c * Bc;

    // ---- link MLP ----
    link1_k<<<(Bc * L_) / 16, 256, 0, stream>>>(xn + bs * L_ * DIN_, link_W1,
                                                link_b1, hbuf);
    linkgemm_k<<<dim3(Bc / 128, 1, L_), 512, 0, stream>>>(
        hbuf, W2T16, link_b2, pe, y32);

    // ---- 4 fused layers (last fuses pooling, skips y32 write) ----
    for (int l = 0; l < NL_ - 1; ++l) {
      layer_k<0><<<dim3(Bc, 1, 1), 512, 0, stream>>>(
          y32,
          Wqkv16 + (size_t)l * 768 * 256, bqkv + l * 768,
          Wo16 + (size_t)l * 256 * 256, bo + l * 256,
          ln1_g + l * 256, ln1_b + l * 256,
          Wff116 + (size_t)l * 1024 * 256, bff1 + l * 1024,
          Wff216 + (size_t)l * 256 * 1024, bff2 + l * 256,
          ln2_g + l * 256, ln2_b + l * 256, nullptr);
    }
    {
      const int l = NL_ - 1;
      layer_k<1><<<dim3(Bc, 1, 1), 512, 0, stream>>>(
          y32,
          Wqkv16 + (size_t)l * 768 * 256, bqkv + l * 768,
          Wo16 + (size_t)l * 256 * 256, bo + l * 256,
          ln1_g + l * 256, ln1_b + l * 256,
          Wff116 + (size_t)l * 1024 * 256, bff1 + l * 1024,
          Wff216 + (size_t)l * 256 * 1024, bff2 + l * 256,
          ln2_g + l * 256, ln2_b + l * 256, pooled + bs * T_);
    }
  }

  // ---- head (fp32) ----
  headgemm_k<<<B_ / 64, 256, 0, stream>>>(pooled, head_W1, head_b1, hh);
  head2_k<<<B_, 64, 0, stream>>>(hh, head_W2, head_b2, (float*)d_out);
}

// Round 22
// 3568.901 us; speedup vs baseline: 1.1271x; 1.1271x over previous
//
#include <hip/hip_runtime.h>
#include <cstddef>

#define B_   4096
#define L_   64
#define T_   256
#define H_   8
#define HD_  32
#define NL_  4
#define DFF_ 1024
#define DIN_ 6

typedef unsigned short ushort_t;
typedef __attribute__((ext_vector_type(8))) short bf16x8;
typedef __attribute__((ext_vector_type(4))) float f32x4;

// ---------------- helpers ----------------
__device__ __forceinline__ float wred_sum(float v) {
#pragma unroll
  for (int off = 32; off >= 1; off >>= 1) v += __shfl_xor(v, off, 64);
  return v;
}
__device__ __forceinline__ ushort_t f2bf(float f) {
  unsigned u = __builtin_bit_cast(unsigned, f);
  u += 0x7fffu + ((u >> 16) & 1u);  // RNE
  return (ushort_t)(u >> 16);
}
__device__ __forceinline__ float bf2f(ushort_t h) {
  unsigned u = ((unsigned)h) << 16;
  return __builtin_bit_cast(float, u);
}
// packed bf16 conversion: low16 = bf16(a), high16 = bf16(b). 1 VALU op.
__device__ __forceinline__ unsigned pk2bf(float a, float b) {
  unsigned r;
  asm volatile("v_cvt_pk_bf16_f32 %0, %1, %2" : "=v"(r) : "v"(a), "v"(b));
  return r;
}
__device__ __forceinline__ void gl16(const ushort_t* g, const ushort_t* l) {
  __builtin_amdgcn_global_load_lds(
      (const __attribute__((address_space(1))) unsigned int*)g,
      (__attribute__((address_space(3))) unsigned int*)l, 16, 0, 0);
}

// ---------------- input normalization (fp32), 4 batch elems/block ---------
__global__ __launch_bounds__(256) void normalize_k(const float* __restrict__ xs,
                                                   float* __restrict__ xn) {
  const int w = threadIdx.x >> 6;
  const int b = blockIdx.x * 4 + w;
  const int l = threadIdx.x & 63;
  const float* x = xs + ((size_t)b * L_ + l) * DIN_;
  const float x0 = x[0], x1 = x[1], x2 = x[2], x3 = x[3], x4 = x[4], x5 = x[5];
  const float prop = fmaxf(x0, 0.f), tx = fmaxf(x1, 0.f);
  const float sp = prop + tx;

  __shared__ float sh[4][64];
  __shared__ float med_sh[4];
  sh[w][l] = sp;
  __syncthreads();
  int rk = 0;
#pragma unroll 8
  for (int j = 0; j < 64; ++j) {
    const float vj = sh[w][j];
    rk += (vj < sp) || (vj == sp && j < l);
  }
  if (rk == 31) med_sh[w] = sp;
  __syncthreads();
  const float t_ref = fmaxf(med_sh[w], 1e-6f);

  float f[5];
  f[0] = prop / t_ref;
  f[1] = tx / t_ref;
  f[2] = x2;
  f[3] = log1pf(fmaxf(x3, 0.f));
  f[4] = log1pf(fmaxf(x4, 0.f) / t_ref);
  const float f5 = log1pf(fmaxf(x5, 0.f));

  float* dst = xn + ((size_t)b * L_ + l) * DIN_;
#pragma unroll
  for (int i = 0; i < 5; ++i) {
    float v = f[i];
    float m = wred_sum(v) * (1.f / 64.f);
    float d = v - m;
    float sd = sqrtf(wred_sum(d * d) * (1.f / 64.f)) + 1e-9f;
    const float lo = m - 3.f * sd, hi = m + 3.f * sd;
    const float cv = fminf(fmaxf(v, lo), hi);
    const float m2 = wred_sum(cv) * (1.f / 64.f);
    const float d2 = cv - m2;
    const float sd2 = sqrtf(wred_sum(d2 * d2) * (1.f / 64.f)) + 1e-9f;
    dst[i] = (cv - m2) / sd2;
  }
  dst[5] = f5;
}

// ---- ALL weight prep fused: wfrag x4 + w2t + pe in one launch ----
// segments: Wqkv 786432 | Wo 262144 | Wff1 1048576 | Wff2 1048576 |
//           W2T 4194304 | pe 8192   -> total 7348224 = 28704 * 256
__global__ __launch_bounds__(256) void prep_k(
    const float* __restrict__ Wqkv, ushort_t* __restrict__ Wqkv16,
    const float* __restrict__ Wo,   ushort_t* __restrict__ Wo16,
    const float* __restrict__ Wff1, ushort_t* __restrict__ Wff116,
    const float* __restrict__ Wff2, ushort_t* __restrict__ Wff216,
    const float* __restrict__ W2,   ushort_t* __restrict__ W2T16,
    float* __restrict__ pe) {
  long idx = (long)blockIdx.x * 256 + threadIdx.x;
  if (idx < 786432) {  // Wqkv frag: NK=196608, K=256
    const int NK = 196608;
    const int z = (int)(idx / NK), r = (int)(idx % NK);
    const int e = r & 7, li = (r >> 3) & 15, t = r >> 7;
    const int ks = t & 31, cb = t >> 5;
    Wqkv16[(size_t)z * NK + r] =
        f2bf(Wqkv[(size_t)z * NK + (size_t)(cb * 16 + li) * 256 + ks * 8 + e]);
    return;
  }
  idx -= 786432;
  if (idx < 262144) {  // Wo frag: NK=65536, K=256
    const int NK = 65536;
    const int z = (int)(idx / NK), r = (int)(idx % NK);
    const int e = r & 7, li = (r >> 3) & 15, t = r >> 7;
    const int ks = t & 31, cb = t >> 5;
    Wo16[(size_t)z * NK + r] =
        f2bf(Wo[(size_t)z * NK + (size_t)(cb * 16 + li) * 256 + ks * 8 + e]);
    return;
  }
  idx -= 262144;
  if (idx < 1048576) {  // Wff1 frag: NK=262144, K=256
    const int NK = 262144;
    const int z = (int)(idx / NK), r = (int)(idx % NK);
    const int e = r & 7, li = (r >> 3) & 15, t = r >> 7;
    const int ks = t & 31, cb = t >> 5;
    Wff116[(size_t)z * NK + r] =
        f2bf(Wff1[(size_t)z * NK + (size_t)(cb * 16 + li) * 256 + ks * 8 + e]);
    return;
  }
  idx -= 1048576;
  if (idx < 1048576) {  // Wff2 frag: NK=262144, K=1024
    const int NK = 262144;
    const int z = (int)(idx / NK), r = (int)(idx % NK);
    const int e = r & 7, li = (r >> 3) & 15, t = r >> 7;
    const int ks = t & 127, cb = t >> 7;
    Wff216[(size_t)z * NK + r] =
        f2bf(Wff2[(size_t)z * NK + (size_t)(cb * 16 + li) * 1024 + ks * 8 + e]);
    return;
  }
  idx -= 1048576;
  if (idx < 4194304) {  // link_W2 transpose per-l
    const int l = (int)(idx >> 16), r = (int)(idx & 65535), s = r >> 8, t = r & 255;
    W2T16[idx] = f2bf(W2[((size_t)l << 16) | (t << 8) | s]);
    return;
  }
  idx -= 4194304;
  if (idx < 8192) {  // positional encoding
    const int l = (int)(idx >> 7), i = (int)(idx & 127);
    const float div = expf(-9.210340371976184f * (2.0f * i) / 256.0f);
    const float ang = (float)l * div;
    pe[l * T_ + 2 * i]     = sinf(ang);
    pe[l * T_ + 2 * i + 1] = cosf(ang);
  }
}

// ---------------- link MLP stage 1: 16 rows/block, coalesced ---------------
__global__ __launch_bounds__(256) void link1_k(const float* __restrict__ xn,
                                               const float* __restrict__ W1,
                                               const float* __restrict__ b1,
                                               ushort_t* __restrict__ h) {
  const size_t r0 = (size_t)blockIdx.x * 16;  // flat row = b*64 + l
  const int col = threadIdx.x;
#pragma unroll
  for (int i = 0; i < 16; ++i) {
    const size_t r = r0 + i;
    const int l = (int)(r & (L_ - 1));
    const float* x = xn + r * DIN_;
    float a = b1[l * T_ + col];
#pragma unroll
    for (int d = 0; d < DIN_; ++d)
      a = fmaf(x[d], W1[((size_t)l * DIN_ + d) * T_ + col], a);
    h[r * T_ + col] = f2bf(fmaxf(a, 0.f));
  }
}

// ---- link GEMM 128x256 tile, z = l, dbuf; epilogue bias+pe -> y32 only ----
__global__ __launch_bounds__(512) void linkgemm_k(
    const ushort_t* __restrict__ A,   // h at (b*64+l)*256 = b*16384 + l*256
    const ushort_t* __restrict__ W,   // W2T16 [l][256][256]
    const float* __restrict__ bias,   // link_b2 [l][256]
    const float* __restrict__ pe,     // [l][256]
    float* __restrict__ y32) {
  __shared__ ushort_t lA[2][4096];
  __shared__ ushort_t lB[2][8192];
  const int tid = threadIdx.x;
  const int lane = tid & 63, w = tid >> 6;
  const int wr = w >> 2, wc = w & 3;
  const size_t b0 = (size_t)blockIdx.x * 128;
  const int l = blockIdx.z;
  const ushort_t* Az = A + b0 * 16384 + (size_t)l * 256;
  const ushort_t* Wz = W + (size_t)l * 65536;

  const int sm = tid >> 6, sks = (tid >> 4) & 3, srr = tid & 15;

  auto stage = [&](int buf, int kt) {
    gl16(Az + (size_t)(16 * sm + srr) * 16384 + kt + sks * 8,
         &lA[buf][(tid & ~63) * 8]);
#pragma unroll
    for (int rd = 0; rd < 2; ++rd) {
      const int nb = sm + rd * 8;
      gl16(Wz + (size_t)(nb * 16 + srr) * 256 + kt + sks * 8,
           &lB[buf][rd * 4096 + (tid & ~63) * 8]);
    }
  };

  f32x4 acc[4][4];
#pragma unroll
  for (int mi = 0; mi < 4; ++mi)
#pragma unroll
    for (int ni = 0; ni < 4; ++ni) acc[mi][ni] = (f32x4){0.f, 0.f, 0.f, 0.f};

  stage(0, 0);
  asm volatile("s_waitcnt vmcnt(0)" ::: "memory");
  __syncthreads();
  int cur = 0;
  for (int t = 0; t < 8; ++t) {
    if (t + 1 < 8) stage(cur ^ 1, (t + 1) << 5);
    bf16x8 af[4], bfr[4];
#pragma unroll
    for (int mi = 0; mi < 4; ++mi)
      af[mi] = *(const bf16x8*)&lA[cur][((wr * 4 + mi) * 64 + lane) * 8];
#pragma unroll
    for (int ni = 0; ni < 4; ++ni)
      bfr[ni] = *(const bf16x8*)&lB[cur][((wc * 4 + ni) * 64 + lane) * 8];
#pragma unroll
    for (int mi = 0; mi < 4; ++mi)
#pragma unroll
      for (int ni = 0; ni < 4; ++ni)
        acc[mi][ni] = __builtin_amdgcn_mfma_f32_16x16x32_bf16(
            af[mi], bfr[ni], acc[mi][ni], 0, 0, 0);
    asm volatile("s_waitcnt vmcnt(0)" ::: "memory");
    __syncthreads();
    cur ^= 1;
  }

  const int r_in = (lane >> 4) * 4;
  const int c_in = lane & 15;
#pragma unroll
  for (int ni = 0; ni < 4; ++ni) {
    const int cg = wc * 64 + ni * 16 + c_in;
    const float bs = bias[l * 256 + cg] + pe[l * 256 + cg];
#pragma unroll
    for (int mi = 0; mi < 4; ++mi) {
#pragma unroll
      for (int rg = 0; rg < 4; ++rg) {
        const size_t bg = b0 + wr * 64 + mi * 16 + r_in + rg;
        y32[bg * 16384 + l * 256 + cg] = acc[mi][ni][rg] + bs;
      }
    }
  }
}

// ==== FULL LAYER: qkv+attn+Wo+LN1+ff1+ff2+LN2, one block per batch elem ====
// LAST=1: skip y32 write, emit pooled[b] (block-local column mean) instead.
template <int LAST>
__global__ __launch_bounds__(256, 2) void layer_k(
    float* __restrict__ y32,
    const ushort_t* __restrict__ Wq, const float* __restrict__ bqkv,
    const ushort_t* __restrict__ Wo, const float* __restrict__ bo,
    const float* __restrict__ ln1g, const float* __restrict__ ln1b,
    const ushort_t* __restrict__ Wf1, const float* __restrict__ bf1,
    const ushort_t* __restrict__ Wf2, const float* __restrict__ bf2,
    const float* __restrict__ ln2g, const float* __restrict__ ln2b,
    float* __restrict__ pool) {
  __shared__ ushort_t yF[16384];     // 32 KB: y / O / y1 frag tile
  __shared__ ushort_t sc[18432];     // 36.9 KB: attn per-wave bufs | zF alias
  __shared__ float red[4][2][64];    // 2 KB
  const int b = blockIdx.x;
  const int tid = threadIdx.x, lane = tid & 63, w = tid >> 6;
  const int li = lane & 15, g = lane >> 4;
  const size_t row0 = (size_t)b * 64;
  const float scale = 0.17677669529663687f;
  ushort_t* bufw = sc + w * 2304;          // Q/K [64][36] then PT [32][72]
  ushort_t* vtw  = sc + 9216 + w * 2304;   // V^T [32][72]
  ushort_t* zF   = sc;                     // ff1 quarter tile (FF phase)

  // ---- stage: y32 -> bf16 frag tile (cvt_pk) ----
#pragma unroll
  for (int j = 0; j < 8; ++j) {
    const int u = j * 256 + tid;
    const int row = u & 63, ks = u >> 6;    // ks in 0..31
    const float* src = y32 + (row0 + row) * 256 + ks * 8;
    const float4 a = *(const float4*)src;
    const float4 c = *(const float4*)(src + 4);
    uint4 v;
    v.x = pk2bf(a.x, a.y);
    v.y = pk2bf(a.z, a.w);
    v.z = pk2bf(c.x, c.y);
    v.w = pk2bf(c.z, c.w);
    *(uint4*)&yF[(((row >> 4) * 32 + ks) * 16 + (row & 15)) * 8] = v;
  }
  __syncthreads();

  // ---- attention phase (4 waves x 2 heads) ----
  f32x4 oa2[2][4][2];
#pragma unroll
  for (int hi = 0; hi < 2; ++hi) {
    const int h = w * 2 + hi, hoff = h * 32;

    f32x4 acc[3][2][4];
#pragma unroll
    for (int m = 0; m < 3; ++m)
#pragma unroll
      for (int n = 0; n < 2; ++n)
#pragma unroll
        for (int mi = 0; mi < 4; ++mi) acc[m][n][mi] = (f32x4){0.f, 0.f, 0.f, 0.f};
    __builtin_amdgcn_s_setprio(1);
#pragma unroll
    for (int kt = 0; kt < 8; ++kt) {
      bf16x8 af[4];
#pragma unroll
      for (int mi = 0; mi < 4; ++mi)
        af[mi] = *(const bf16x8*)&yF[((mi * 32 + kt * 4 + g) * 16 + li) * 8];
      bf16x8 bw[3][2];
#pragma unroll
      for (int m = 0; m < 3; ++m)
#pragma unroll
        for (int n = 0; n < 2; ++n)
          bw[m][n] = *(const bf16x8*)(Wq +
              (size_t)(((m * 16 + 2 * h + n) * 32 + kt * 4 + g) * 16 + li) * 8);
#pragma unroll
      for (int m = 0; m < 3; ++m)
#pragma unroll
        for (int n = 0; n < 2; ++n)
#pragma unroll
          for (int mi = 0; mi < 4; ++mi)
            acc[m][n][mi] = __builtin_amdgcn_mfma_f32_16x16x32_bf16(
                af[mi], bw[m][n], acc[m][n][mi], 0, 0, 0);
    }
    __builtin_amdgcn_s_setprio(0);
    float bs[3][2];
#pragma unroll
    for (int m = 0; m < 3; ++m)
#pragma unroll
      for (int n = 0; n < 2; ++n) bs[m][n] = bqkv[m * 256 + hoff + 16 * n + li];

    // Q -> bufw [64][36], read qb
#pragma unroll
    for (int n = 0; n < 2; ++n)
#pragma unroll
      for (int mi = 0; mi < 4; ++mi) {
        const unsigned p0 = pk2bf(acc[0][n][mi][0] + bs[0][n],
                                  acc[0][n][mi][1] + bs[0][n]);
        const unsigned p1 = pk2bf(acc[0][n][mi][2] + bs[0][n],
                                  acc[0][n][mi][3] + bs[0][n]);
        const int base = (16 * mi + 4 * g) * 36 + 16 * n + li;
        bufw[base]       = (ushort_t)p0;
        bufw[base + 36]  = (ushort_t)(p0 >> 16);
        bufw[base + 72]  = (ushort_t)p1;
        bufw[base + 108] = (ushort_t)(p1 >> 16);
      }
    bf16x8 qb[4];
#pragma unroll
    for (int ni = 0; ni < 4; ++ni)
      qb[ni] = *(const bf16x8*)&bufw[(16 * ni + li) * 36 + g * 8];

    // K -> bufw (overwrite), read ka
#pragma unroll
    for (int n = 0; n < 2; ++n)
#pragma unroll
      for (int mi = 0; mi < 4; ++mi) {
        const unsigned p0 = pk2bf(acc[1][n][mi][0] + bs[1][n],
                                  acc[1][n][mi][1] + bs[1][n]);
        const unsigned p1 = pk2bf(acc[1][n][mi][2] + bs[1][n],
                                  acc[1][n][mi][3] + bs[1][n]);
        const int base = (16 * mi + 4 * g) * 36 + 16 * n + li;
        bufw[base]       = (ushort_t)p0;
        bufw[base + 36]  = (ushort_t)(p0 >> 16);
        bufw[base + 72]  = (ushort_t)p1;
        bufw[base + 108] = (ushort_t)(p1 >> 16);
      }
    bf16x8 ka[4];
#pragma unroll
    for (int mi = 0; mi < 4; ++mi)
      ka[mi] = *(const bf16x8*)&bufw[(16 * mi + li) * 36 + g * 8];

    // V^T -> vtw [32][72] (contiguous in r -> uint2 store), read vb
#pragma unroll
    for (int n = 0; n < 2; ++n)
#pragma unroll
      for (int mi = 0; mi < 4; ++mi) {
        const unsigned p0 = pk2bf(acc[2][n][mi][0] + bs[2][n],
                                  acc[2][n][mi][1] + bs[2][n]);
        const unsigned p1 = pk2bf(acc[2][n][mi][2] + bs[2][n],
                                  acc[2][n][mi][3] + bs[2][n]);
        *(uint2*)&vtw[(16 * n + li) * 72 + 16 * mi + 4 * g] = make_uint2(p0, p1);
      }
    bf16x8 vb[2][2];
#pragma unroll
    for (int ks = 0; ks < 2; ++ks)
#pragma unroll
      for (int n2 = 0; n2 < 2; ++n2)
        vb[ks][n2] = *(const bf16x8*)&vtw[(16 * n2 + li) * 72 + ks * 32 + g * 8];

#pragma unroll
    for (int mi = 0; mi < 4; ++mi)
#pragma unroll
      for (int n2 = 0; n2 < 2; ++n2) oa2[hi][mi][n2] = (f32x4){0.f, 0.f, 0.f, 0.f};

#pragma unroll
    for (int half = 0; half < 2; ++half) {
      f32x4 s[4][2];
      __builtin_amdgcn_s_setprio(1);
#pragma unroll
      for (int mi = 0; mi < 4; ++mi)
#pragma unroll
        for (int nn = 0; nn < 2; ++nn)
          s[mi][nn] = __builtin_amdgcn_mfma_f32_16x16x32_bf16(
              ka[mi], qb[2 * half + nn], (f32x4){0.f, 0.f, 0.f, 0.f}, 0, 0, 0);
      __builtin_amdgcn_s_setprio(0);

#pragma unroll
      for (int nn = 0; nn < 2; ++nn) {
        float mx = -3.4e38f;
#pragma unroll
        for (int mi = 0; mi < 4; ++mi)
#pragma unroll
          for (int r = 0; r < 4; ++r) {
            s[mi][nn][r] *= scale;
            mx = fmaxf(mx, s[mi][nn][r]);
          }
        mx = fmaxf(mx, __shfl_xor(mx, 16, 64));
        mx = fmaxf(mx, __shfl_xor(mx, 32, 64));
        float sum = 0.f;
#pragma unroll
        for (int mi = 0; mi < 4; ++mi)
#pragma unroll
          for (int r = 0; r < 4; ++r) {
            const float e = expf(s[mi][nn][r] - mx);
            s[mi][nn][r] = e;
            sum += e;
          }
        sum += __shfl_xor(sum, 16, 64);
        sum += __shfl_xor(sum, 32, 64);
        const float inv = 1.f / sum;
        const int qrow = 16 * nn + li;
#pragma unroll
        for (int mi = 0; mi < 4; ++mi) {
          const unsigned lo = pk2bf(s[mi][nn][0] * inv, s[mi][nn][1] * inv);
          const unsigned hi2 = pk2bf(s[mi][nn][2] * inv, s[mi][nn][3] * inv);
          *(uint2*)&bufw[qrow * 72 + 16 * mi + 4 * g] = make_uint2(lo, hi2);
        }
      }

      __builtin_amdgcn_s_setprio(1);
#pragma unroll
      for (int ks = 0; ks < 2; ++ks) {
        bf16x8 pa[2];
#pragma unroll
        for (int m2 = 0; m2 < 2; ++m2)
          pa[m2] = *(const bf16x8*)&bufw[(16 * m2 + li) * 72 + ks * 32 + g * 8];
#pragma unroll
        for (int m2 = 0; m2 < 2; ++m2)
#pragma unroll
          for (int n2 = 0; n2 < 2; ++n2)
            oa2[hi][2 * half + m2][n2] = __builtin_amdgcn_mfma_f32_16x16x32_bf16(
                pa[m2], vb[ks][n2], oa2[hi][2 * half + m2][n2], 0, 0, 0);
      }
      __builtin_amdgcn_s_setprio(0);
    }
  }

  __syncthreads();  // all yF reads + sc use complete
  // O -> yF fragment order
#pragma unroll
  for (int hi = 0; hi < 2; ++hi) {
    const int hoff = (2 * w + hi) * 32;
#pragma unroll
    for (int mi = 0; mi < 4; ++mi)
#pragma unroll
      for (int n2 = 0; n2 < 2; ++n2) {
        const unsigned p0 = pk2bf(oa2[hi][mi][n2][0], oa2[hi][mi][n2][1]);
        const unsigned p1 = pk2bf(oa2[hi][mi][n2][2], oa2[hi][mi][n2][3]);
        const int col = hoff + 16 * n2 + li;
        const int base = ((mi * 32 + (col >> 3)) * 16 + 4 * g) * 8 + (col & 7);
        yF[base]      = (ushort_t)p0;
        yF[base + 8]  = (ushort_t)(p0 >> 16);
        yF[base + 16] = (ushort_t)p1;
        yF[base + 24] = (ushort_t)(p1 >> 16);
      }
  }
  __syncthreads();

  // ---- Wo GEMM: wave w -> cols [64w, 64w+64), K=256 ----
  f32x4 acc[4][4];
#pragma unroll
  for (int mi = 0; mi < 4; ++mi)
#pragma unroll
    for (int ni = 0; ni < 4; ++ni) acc[mi][ni] = (f32x4){0.f, 0.f, 0.f, 0.f};
  __builtin_amdgcn_s_setprio(1);
#pragma unroll
  for (int kt = 0; kt < 8; ++kt) {
    bf16x8 af[4], bfr[4];
#pragma unroll
    for (int mi = 0; mi < 4; ++mi)
      af[mi] = *(const bf16x8*)&yF[((mi * 32 + kt * 4 + g) * 16 + li) * 8];
#pragma unroll
    for (int ni = 0; ni < 4; ++ni)
      bfr[ni] = *(const bf16x8*)(Wo +
          (size_t)(((4 * w + ni) * 32 + kt * 4 + g) * 16 + li) * 8);
#pragma unroll
    for (int mi = 0; mi < 4; ++mi)
#pragma unroll
      for (int ni = 0; ni < 4; ++ni)
        acc[mi][ni] = __builtin_amdgcn_mfma_f32_16x16x32_bf16(
            af[mi], bfr[ni], acc[mi][ni], 0, 0, 0);
  }
  __builtin_amdgcn_s_setprio(0);

  // ---- LN1: residual from y32, y1 -> registers (fp32) ----
  const int r_in = (lane >> 4) * 4;
  const int c_in = lane & 15;
  float y1r[4][4][4];
#pragma unroll
  for (int mi = 0; mi < 4; ++mi) {
#pragma unroll
    for (int rg = 0; rg < 4; ++rg) {
      const int row_l = 16 * mi + r_in + rg;
      float s1 = 0.f, s2 = 0.f;
#pragma unroll
      for (int ni = 0; ni < 4; ++ni) {
        const int cg = 64 * w + 16 * ni + c_in;
        const float zv = acc[mi][ni][rg] + bo[cg] + y32[(row0 + row_l) * 256 + cg];
        acc[mi][ni][rg] = zv;
        s1 += zv;
        s2 += zv * zv;
      }
#pragma unroll
      for (int off = 1; off <= 8; off <<= 1) {
        s1 += __shfl_xor(s1, off, 64);
        s2 += __shfl_xor(s2, off, 64);
      }
      if (c_in == 0) {
        red[w][0][row_l] = s1;
        red[w][1][row_l] = s2;
      }
    }
  }
  __syncthreads();  // also: all Wo yF reads complete
#pragma unroll
  for (int mi = 0; mi < 4; ++mi) {
#pragma unroll
    for (int rg = 0; rg < 4; ++rg) {
      const int row_l = 16 * mi + r_in + rg;
      const float S1 = red[0][0][row_l] + red[1][0][row_l] + red[2][0][row_l] + red[3][0][row_l];
      const float S2 = red[0][1][row_l] + red[1][1][row_l] + red[2][1][row_l] + red[3][1][row_l];
      const float m = S1 * (1.f / 256.f);
      const float var = S2 * (1.f / 256.f) - m * m;
      const float rs = rsqrtf(var + 1e-5f);
      float tv[4];
#pragma unroll
      for (int ni = 0; ni < 4; ++ni) {
        const int cg = 64 * w + 16 * ni + c_in;
        tv[ni] = (acc[mi][ni][rg] - m) * rs * ln1g[cg] + ln1b[cg];
        y1r[mi][ni][rg] = tv[ni];
      }
      const unsigned p0 = pk2bf(tv[0], tv[1]);
      const unsigned p1 = pk2bf(tv[2], tv[3]);
#pragma unroll
      for (int ni = 0; ni < 4; ++ni) {
        const int cg = 64 * w + 16 * ni + c_in;
        const unsigned pk = (ni < 2) ? p0 : p1;
        const ushort_t hv = (ni & 1) ? (ushort_t)(pk >> 16) : (ushort_t)pk;
        yF[((mi * 32 + (cg >> 3)) * 16 + (row_l & 15)) * 8 + (cg & 7)] = hv;
      }
    }
  }
  __syncthreads();

  // ---- FF phase: ff1 quarters (zF in sc) + ff2 accumulate ----
  f32x4 acc2[4][4];
#pragma unroll
  for (int mi = 0; mi < 4; ++mi)
#pragma unroll
    for (int ni = 0; ni < 4; ++ni) acc2[mi][ni] = (f32x4){0.f, 0.f, 0.f, 0.f};

#pragma unroll 1
  for (int q = 0; q < 4; ++q) {
#pragma unroll 1
    for (int p = 0; p < 2; ++p) {
      // ff1: cols [256q + 64w + 32p, +32)
      f32x4 acc1[4][2];
#pragma unroll
      for (int mi = 0; mi < 4; ++mi)
#pragma unroll
        for (int n = 0; n < 2; ++n) acc1[mi][n] = (f32x4){0.f, 0.f, 0.f, 0.f};
      __builtin_amdgcn_s_setprio(1);
#pragma unroll
      for (int kt = 0; kt < 8; ++kt) {
        bf16x8 af[4], bw[2];
#pragma unroll
        for (int mi = 0; mi < 4; ++mi)
          af[mi] = *(const bf16x8*)&yF[((mi * 32 + kt * 4 + g) * 16 + li) * 8];
#pragma unroll
        for (int n = 0; n < 2; ++n)
          bw[n] = *(const bf16x8*)(Wf1 +
              (size_t)(((16 * q + 4 * w + 2 * p + n) * 32 + kt * 4 + g) * 16 + li) * 8);
#pragma unroll
        for (int mi = 0; mi < 4; ++mi)
#pragma unroll
          for (int n = 0; n < 2; ++n)
            acc1[mi][n] = __builtin_amdgcn_mfma_f32_16x16x32_bf16(
                af[mi], bw[n], acc1[mi][n], 0, 0, 0);
      }
      __builtin_amdgcn_s_setprio(0);
      if (q && p == 0) __syncthreads();  // prior quarter's zF reads complete
      // relu+bias -> zF frag order (kk = local col in quarter)
#pragma unroll
      for (int n = 0; n < 2; ++n) {
        const int kk = 64 * w + 32 * p + 16 * n + li;
        const float bb = bf1[256 * q + kk];
#pragma unroll
        for (int mi = 0; mi < 4; ++mi) {
          const unsigned p0 = pk2bf(fmaxf(acc1[mi][n][0] + bb, 0.f),
                                    fmaxf(acc1[mi][n][1] + bb, 0.f));
          const unsigned p1 = pk2bf(fmaxf(acc1[mi][n][2] + bb, 0.f),
                                    fmaxf(acc1[mi][n][3] + bb, 0.f));
          const int base = ((mi * 32 + (kk >> 3)) * 16 + 4 * g) * 8 + (kk & 7);
          zF[base]      = (ushort_t)p0;
          zF[base + 8]  = (ushort_t)(p0 >> 16);
          zF[base + 16] = (ushort_t)p1;
          zF[base + 24] = (ushort_t)(p1 >> 16);
        }
      }
    }
    __syncthreads();
    // ff2 partial: K-slice [256q, +256), wave w -> out cols [64w, 64w+64)
    __builtin_amdgcn_s_setprio(1);
#pragma unroll
    for (int kt = 0; kt < 8; ++kt) {
      bf16x8 af2[4], bw2[4];
#pragma unroll
      for (int mi = 0; mi < 4; ++mi)
        af2[mi] = *(const bf16x8*)&zF[((mi * 32 + kt * 4 + g) * 16 + li) * 8];
#pragma unroll
      for (int ni = 0; ni < 4; ++ni)
        bw2[ni] = *(const bf16x8*)(Wf2 +
            (size_t)(((4 * w + ni) * 128 + 32 * q + kt * 4 + g) * 16 + li) * 8);
#pragma unroll
      for (int mi = 0; mi < 4; ++mi)
#pragma unroll
        for (int ni = 0; ni < 4; ++ni)
          acc2[mi][ni] = __builtin_amdgcn_mfma_f32_16x16x32_bf16(
              af2[mi], bw2[ni], acc2[mi][ni], 0, 0, 0);
    }
    __builtin_amdgcn_s_setprio(0);
  }

  // ---- LN2: residual = y1r (fp32 regs); write y32 or pooled ----
#pragma unroll
  for (int mi = 0; mi < 4; ++mi) {
#pragma unroll
    for (int rg = 0; rg < 4; ++rg) {
      const int row_l = 16 * mi + r_in + rg;
      float s1 = 0.f, s2 = 0.f;
#pragma unroll
      for (int ni = 0; ni < 4; ++ni) {
        const int cg = 64 * w + 16 * ni + c_in;
        const float zv = acc2[mi][ni][rg] + bf2[cg] + y1r[mi][ni][rg];
        acc2[mi][ni][rg] = zv;
        s1 += zv;
        s2 += zv * zv;
      }
#pragma unroll
      for (int off = 1; off <= 8; off <<= 1) {
        s1 += __shfl_xor(s1, off, 64);
        s2 += __shfl_xor(s2, off, 64);
      }
      if (c_in == 0) {
        red[w][0][row_l] = s1;
        red[w][1][row_l] = s2;
      }
    }
  }
  __syncthreads();
  float colsum[4] = {0.f, 0.f, 0.f, 0.f};
#pragma unroll
  for (int mi = 0; mi < 4; ++mi) {
#pragma unroll
    for (int rg = 0; rg < 4; ++rg) {
      const int row_l = 16 * mi + r_in + rg;
      const float S1 = red[0][0][row_l] + red[1][0][row_l] + red[2][0][row_l] + red[3][0][row_l];
      const float S2 = red[0][1][row_l] + red[1][1][row_l] + red[2][1][row_l] + red[3][1][row_l];
      const float m = S1 * (1.f / 256.f);
      const float var = S2 * (1.f / 256.f) - m * m;
      const float rs = rsqrtf(var + 1e-5f);
#pragma unroll
      for (int ni = 0; ni < 4; ++ni) {
        const int cg = 64 * w + 16 * ni + c_in;
        const float v = (acc2[mi][ni][rg] - m) * rs * ln2g[cg] + ln2b[cg];
        if constexpr (LAST) {
          colsum[ni] += v;
        } else {
          y32[(row0 + row_l) * 256 + cg] = v;
        }
      }
    }
  }
  if constexpr (LAST) {
    // sum across the 4 row-groups (lanes c_in+16g) -> full 64-row column sum
#pragma unroll
    for (int ni = 0; ni < 4; ++ni) {
      float s = colsum[ni];
      s += __shfl_xor(s, 16, 64);
      s += __shfl_xor(s, 32, 64);
      if (g == 0) pool[(size_t)b * 256 + 64 * w + 16 * ni + c_in] = s * (1.f / 64.f);
    }
  }
}

// ---------------- fp32 head GEMM (64-row tile, relu) ----------------
__global__ __launch_bounds__(256) void headgemm_k(
    const float* __restrict__ A, const float* __restrict__ Wt,
    const float* __restrict__ bias, float* __restrict__ out) {
  const int tid = threadIdx.x;
  const int tx = tid & 63, ty = tid >> 6;
  const int cfull = tx * 4;
  const size_t b0 = (size_t)blockIdx.x * 64;

  __shared__ float At[256][68];

  float4 acc[16];
#pragma unroll
  for (int r = 0; r < 16; ++r) acc[r] = make_float4(0.f, 0.f, 0.f, 0.f);
  const int r0 = ty * 16;

  {
    const int rr = tid >> 6;
    const int k4 = (tid & 63) * 4;
#pragma unroll
    for (int p = 0; p < 16; ++p) {
      const int r = p * 4 + rr;
      const float4 v = *(const float4*)(A + (b0 + r) * 256 + k4);
      At[k4 + 0][r] = v.x;
      At[k4 + 1][r] = v.y;
      At[k4 + 2][r] = v.z;
      At[k4 + 3][r] = v.w;
    }
  }
  __syncthreads();
  const float* wp = Wt + cfull;
#pragma unroll 2
  for (int k = 0; k < 256; ++k) {
    const float4 w = *(const float4*)wp;
    wp += 256;
    const float4* ar = (const float4*)(&At[k][r0]);
    const float4 a0 = ar[0], a1 = ar[1], a2 = ar[2], a3 = ar[3];
    const float av[16] = {a0.x, a0.y, a0.z, a0.w, a1.x, a1.y, a1.z, a1.w,
                          a2.x, a2.y, a2.z, a2.w, a3.x, a3.y, a3.z, a3.w};
#pragma unroll
    for (int r = 0; r < 16; ++r) {
      acc[r].x = fmaf(av[r], w.x, acc[r].x);
      acc[r].y = fmaf(av[r], w.y, acc[r].y);
      acc[r].z = fmaf(av[r], w.z, acc[r].z);
      acc[r].w = fmaf(av[r], w.w, acc[r].w);
    }
  }
  const float4 bb = *(const float4*)(bias + cfull);
#pragma unroll
  for (int r = 0; r < 16; ++r) {
    const size_t row = b0 + r0 + r;
    float4 o;
    o.x = fmaxf(acc[r].x + bb.x, 0.f);
    o.y = fmaxf(acc[r].y + bb.y, 0.f);
    o.z = fmaxf(acc[r].z + bb.z, 0.f);
    o.w = fmaxf(acc[r].w + bb.w, 0.f);
    *(float4*)(out + row * 256 + cfull) = o;
  }
}

__global__ __launch_bounds__(64) void head2_k(const float* __restrict__ hh,
                                              const float* __restrict__ W2,
                                              const float* __restrict__ b2,
                                              float* __restrict__ out) {
  const size_t b = blockIdx.x;
  const int lane = threadIdx.x;
  const float4 hv = *(const float4*)(hh + b * T_ + lane * 4);
  const float4 wv = *(const float4*)(W2 + lane * 4);
  float s = hv.x * wv.x + hv.y * wv.y + hv.z * wv.z + hv.w * wv.w;
  s = wred_sum(s);
  if (lane == 0) out[b] = s + b2[0];
}

// ---------------- launch ----------------
extern "C" void kernel_launch(void* const* d_in, const int* in_sizes, int n_in,
                              void* d_out, int out_size, void* d_ws, size_t ws_size,
                              hipStream_t stream) {
  const float* link_states = (const float*)d_in[0];
  const float* link_W1 = (const float*)d_in[1];
  const float* link_b1 = (const float*)d_in[2];
  const float* link_W2 = (const float*)d_in[3];
  const float* link_b2 = (const float*)d_in[4];
  const float* Wqkv = (const float*)d_in[5];
  const float* bqkv = (const float*)d_in[6];
  const float* Wo = (const float*)d_in[7];
  const float* bo = (const float*)d_in[8];
  const float* ln1_g = (const float*)d_in[9];
  const float* ln1_b = (const float*)d_in[10];
  const float* Wff1 = (const float*)d_in[11];
  const float* bff1 = (const float*)d_in[12];
  const float* Wff2 = (const float*)d_in[13];
  const float* bff2 = (const float*)d_in[14];
  const float* ln2_g = (const float*)d_in[15];
  const float* ln2_b = (const float*)d_in[16];
  const float* head_W1 = (const float*)d_in[17];
  const float* head_b1 = (const float*)d_in[18];
  const float* head_W2 = (const float*)d_in[19];
  const float* head_b2 = (const float*)d_in[20];

  char* base = (char*)d_ws;
  size_t off = 0;
  auto alloc = [&](size_t bytes) -> char* {
    char* p = base + off;
    off = (off + bytes + 255) & ~(size_t)255;
    return p;
  };

  // ---- fixed region (~29.4 MB) ----
  ushort_t* Wqkv16 = (ushort_t*)alloc((size_t)NL_ * 768 * 256 * 2);
  ushort_t* Wo16   = (ushort_t*)alloc((size_t)NL_ * 256 * 256 * 2);
  ushort_t* Wff116 = (ushort_t*)alloc((size_t)NL_ * 1024 * 256 * 2);
  ushort_t* Wff216 = (ushort_t*)alloc((size_t)NL_ * 256 * 1024 * 2);
  ushort_t* W2T16  = (ushort_t*)alloc((size_t)L_ * 256 * 256 * 2);
  float* pe     = (float*)alloc((size_t)L_ * T_ * 4);
  float* xn     = (float*)alloc((size_t)B_ * L_ * DIN_ * 4);
  float* pooled = (float*)alloc((size_t)B_ * T_ * 4);
  float* hh     = (float*)alloc((size_t)B_ * T_ * 4);

  // ---- chunked region: 98,304 B per batch element (y32 + hbuf) ----
  const size_t fixed_end = off;
  const size_t availB = (ws_size > fixed_end + 65536) ? (ws_size - fixed_end - 65536) : 0;
  int NC = 1;
  while (NC < 32 && (size_t)(B_ / NC) * 98304ull > availB) NC <<= 1;
  const int Bc = B_ / NC;

  float*    y32  = (float*)alloc((size_t)Bc * L_ * T_ * 4);
  ushort_t* hbuf = (ushort_t*)alloc((size_t)Bc * L_ * T_ * 2);

  // ---- prep: all weight transforms + pe in ONE launch ----
  prep_k<<<28704, 256, 0, stream>>>(Wqkv, Wqkv16, Wo, Wo16, Wff1, Wff116,
                                    Wff2, Wff216, link_W2, W2T16, pe);
  normalize_k<<<B_ / 4, 256, 0, stream>>>(link_states, xn);

  for (int c = 0; c < NC; ++c) {
    const size_t bs = (size_t)c * Bc;

    // ---- link MLP ----
    link1_k<<<(Bc * L_) / 16, 256, 0, stream>>>(xn + bs * L_ * DIN_, link_W1,
                                                link_b1, hbuf);
    linkgemm_k<<<dim3(Bc / 128, 1, L_), 512, 0, stream>>>(
        hbuf, W2T16, link_b2, pe, y32);

    // ---- 4 fused layers (last fuses pooling, skips y32 write) ----
    for (int l = 0; l < NL_ - 1; ++l) {
      layer_k<0><<<dim3(Bc, 1, 1), 256, 0, stream>>>(
          y32,
          Wqkv16 + (size_t)l * 768 * 256, bqkv + l * 768,
          Wo16 + (size_t)l * 256 * 256, bo + l * 256,
          ln1_g + l * 256, ln1_b + l * 256,
          Wff116 + (size_t)l * 1024 * 256, bff1 + l * 1024,
          Wff216 + (size_t)l * 256 * 1024, bff2 + l * 256,
          ln2_g + l * 256, ln2_b + l * 256, nullptr);
    }
    {
      const int l = NL_ - 1;
      layer_k<1><<<dim3(Bc, 1, 1), 256, 0, stream>>>(
          y32,
          Wqkv16 + (size_t)l * 768 * 256, bqkv + l * 768,
          Wo16 + (size_t)l * 256 * 256, bo + l * 256,
          ln1_g + l * 256, ln1_b + l * 256,
          Wff116 + (size_t)l * 1024 * 256, bff1 + l * 1024,
          Wff216 + (size_t)l * 256 * 1024, bff2 + l * 256,
          ln2_g + l * 256, ln2_b + l * 256, pooled + bs * T_);
    }
  }

  // ---- head (fp32) ----
  headgemm_k<<<B_ / 64, 256, 0, stream>>>(pooled, head_W1, head_b1, hh);
  head2_k<<<B_, 64, 0, stream>>>(hh, head_W2, head_b2, (float*)d_out);
}

// Round 23
// 3511.459 us; speedup vs baseline: 1.1455x; 1.0164x over previous
//
#include <hip/hip_runtime.h>
#include <cstddef>

#define B_   4096
#define L_   64
#define T_   256
#define H_   8
#define HD_  32
#define NL_  4
#define DFF_ 1024
#define DIN_ 6

typedef unsigned short ushort_t;
typedef __attribute__((ext_vector_type(8))) short bf16x8;
typedef __attribute__((ext_vector_type(4))) float f32x4;

// ---------------- helpers ----------------
__device__ __forceinline__ float wred_sum(float v) {
#pragma unroll
  for (int off = 32; off >= 1; off >>= 1) v += __shfl_xor(v, off, 64);
  return v;
}
__device__ __forceinline__ ushort_t f2bf(float f) {
  unsigned u = __builtin_bit_cast(unsigned, f);
  u += 0x7fffu + ((u >> 16) & 1u);  // RNE
  return (ushort_t)(u >> 16);
}
__device__ __forceinline__ float bf2f(ushort_t h) {
  unsigned u = ((unsigned)h) << 16;
  return __builtin_bit_cast(float, u);
}
// packed bf16 conversion: low16 = bf16(a), high16 = bf16(b). 1 VALU op.
__device__ __forceinline__ unsigned pk2bf(float a, float b) {
  unsigned r;
  asm volatile("v_cvt_pk_bf16_f32 %0, %1, %2" : "=v"(r) : "v"(a), "v"(b));
  return r;
}
__device__ __forceinline__ void gl16(const ushort_t* g, const ushort_t* l) {
  __builtin_amdgcn_global_load_lds(
      (const __attribute__((address_space(1))) unsigned int*)g,
      (__attribute__((address_space(3))) unsigned int*)l, 16, 0, 0);
}

// ---------------- input normalization (fp32), 4 batch elems/block ---------
__global__ __launch_bounds__(256) void normalize_k(const float* __restrict__ xs,
                                                   float* __restrict__ xn) {
  const int w = threadIdx.x >> 6;
  const int b = blockIdx.x * 4 + w;
  const int l = threadIdx.x & 63;
  const float* x = xs + ((size_t)b * L_ + l) * DIN_;
  const float x0 = x[0], x1 = x[1], x2 = x[2], x3 = x[3], x4 = x[4], x5 = x[5];
  const float prop = fmaxf(x0, 0.f), tx = fmaxf(x1, 0.f);
  const float sp = prop + tx;

  __shared__ float sh[4][64];
  __shared__ float med_sh[4];
  sh[w][l] = sp;
  __syncthreads();
  int rk = 0;
#pragma unroll 8
  for (int j = 0; j < 64; ++j) {
    const float vj = sh[w][j];
    rk += (vj < sp) || (vj == sp && j < l);
  }
  if (rk == 31) med_sh[w] = sp;
  __syncthreads();
  const float t_ref = fmaxf(med_sh[w], 1e-6f);

  float f[5];
  f[0] = prop / t_ref;
  f[1] = tx / t_ref;
  f[2] = x2;
  f[3] = log1pf(fmaxf(x3, 0.f));
  f[4] = log1pf(fmaxf(x4, 0.f) / t_ref);
  const float f5 = log1pf(fmaxf(x5, 0.f));

  float* dst = xn + ((size_t)b * L_ + l) * DIN_;
#pragma unroll
  for (int i = 0; i < 5; ++i) {
    float v = f[i];
    float m = wred_sum(v) * (1.f / 64.f);
    float d = v - m;
    float sd = sqrtf(wred_sum(d * d) * (1.f / 64.f)) + 1e-9f;
    const float lo = m - 3.f * sd, hi = m + 3.f * sd;
    const float cv = fminf(fmaxf(v, lo), hi);
    const float m2 = wred_sum(cv) * (1.f / 64.f);
    const float d2 = cv - m2;
    const float sd2 = sqrtf(wred_sum(d2 * d2) * (1.f / 64.f)) + 1e-9f;
    dst[i] = (cv - m2) / sd2;
  }
  dst[5] = f5;
}

// ---- ALL weight prep fused: wfrag x4 + w2t + pe in one launch ----
__global__ __launch_bounds__(256) void prep_k(
    const float* __restrict__ Wqkv, ushort_t* __restrict__ Wqkv16,
    const float* __restrict__ Wo,   ushort_t* __restrict__ Wo16,
    const float* __restrict__ Wff1, ushort_t* __restrict__ Wff116,
    const float* __restrict__ Wff2, ushort_t* __restrict__ Wff216,
    const float* __restrict__ W2,   ushort_t* __restrict__ W2T16,
    float* __restrict__ pe) {
  long idx = (long)blockIdx.x * 256 + threadIdx.x;
  if (idx < 786432) {  // Wqkv frag: NK=196608, K=256
    const int NK = 196608;
    const int z = (int)(idx / NK), r = (int)(idx % NK);
    const int e = r & 7, li = (r >> 3) & 15, t = r >> 7;
    const int ks = t & 31, cb = t >> 5;
    Wqkv16[(size_t)z * NK + r] =
        f2bf(Wqkv[(size_t)z * NK + (size_t)(cb * 16 + li) * 256 + ks * 8 + e]);
    return;
  }
  idx -= 786432;
  if (idx < 262144) {  // Wo frag: NK=65536, K=256
    const int NK = 65536;
    const int z = (int)(idx / NK), r = (int)(idx % NK);
    const int e = r & 7, li = (r >> 3) & 15, t = r >> 7;
    const int ks = t & 31, cb = t >> 5;
    Wo16[(size_t)z * NK + r] =
        f2bf(Wo[(size_t)z * NK + (size_t)(cb * 16 + li) * 256 + ks * 8 + e]);
    return;
  }
  idx -= 262144;
  if (idx < 1048576) {  // Wff1 frag: NK=262144, K=256
    const int NK = 262144;
    const int z = (int)(idx / NK), r = (int)(idx % NK);
    const int e = r & 7, li = (r >> 3) & 15, t = r >> 7;
    const int ks = t & 31, cb = t >> 5;
    Wff116[(size_t)z * NK + r] =
        f2bf(Wff1[(size_t)z * NK + (size_t)(cb * 16 + li) * 256 + ks * 8 + e]);
    return;
  }
  idx -= 1048576;
  if (idx < 1048576) {  // Wff2 frag: NK=262144, K=1024
    const int NK = 262144;
    const int z = (int)(idx / NK), r = (int)(idx % NK);
    const int e = r & 7, li = (r >> 3) & 15, t = r >> 7;
    const int ks = t & 127, cb = t >> 7;
    Wff216[(size_t)z * NK + r] =
        f2bf(Wff2[(size_t)z * NK + (size_t)(cb * 16 + li) * 1024 + ks * 8 + e]);
    return;
  }
  idx -= 1048576;
  if (idx < 4194304) {  // link_W2 transpose per-l
    const int l = (int)(idx >> 16), r = (int)(idx & 65535), s = r >> 8, t = r & 255;
    W2T16[idx] = f2bf(W2[((size_t)l << 16) | (t << 8) | s]);
    return;
  }
  idx -= 4194304;
  if (idx < 8192) {  // positional encoding
    const int l = (int)(idx >> 7), i = (int)(idx & 127);
    const float div = expf(-9.210340371976184f * (2.0f * i) / 256.0f);
    const float ang = (float)l * div;
    pe[l * T_ + 2 * i]     = sinf(ang);
    pe[l * T_ + 2 * i + 1] = cosf(ang);
  }
}

// ---------------- link MLP stage 1: 16 rows/block, h stored l-major --------
// h layout: [l][b_local][256]  (so linkgemm's per-l A-tiles are contiguous)
__global__ __launch_bounds__(256) void link1_k(const float* __restrict__ xn,
                                               const float* __restrict__ W1,
                                               const float* __restrict__ b1,
                                               ushort_t* __restrict__ h,
                                               int Bc) {
  const size_t r0 = (size_t)blockIdx.x * 16;  // flat row = bloc*64 + l
  const int col = threadIdx.x;
#pragma unroll
  for (int i = 0; i < 16; ++i) {
    const size_t r = r0 + i;
    const int l = (int)(r & (L_ - 1));
    const size_t bloc = r >> 6;
    const float* x = xn + r * DIN_;
    float a = b1[l * T_ + col];
#pragma unroll
    for (int d = 0; d < DIN_; ++d)
      a = fmaf(x[d], W1[((size_t)l * DIN_ + d) * T_ + col], a);
    h[((size_t)l * Bc + bloc) * T_ + col] = f2bf(fmaxf(a, 0.f));
  }
}

// ---- link GEMM 128x256 tile, z = l, dbuf; A rows contiguous (l-major h) ---
__global__ __launch_bounds__(512) void linkgemm_k(
    const ushort_t* __restrict__ A,   // h [l][b][256]
    const ushort_t* __restrict__ W,   // W2T16 [l][256][256]
    const float* __restrict__ bias,   // link_b2 [l][256]
    const float* __restrict__ pe,     // [l][256]
    float* __restrict__ y32, int Bc) {
  __shared__ ushort_t lA[2][4096];
  __shared__ ushort_t lB[2][8192];
  const int tid = threadIdx.x;
  const int lane = tid & 63, w = tid >> 6;
  const int wr = w >> 2, wc = w & 3;
  const size_t b0 = (size_t)blockIdx.x * 128;
  const int l = blockIdx.z;
  const ushort_t* Az = A + ((size_t)l * Bc + b0) * 256;
  const ushort_t* Wz = W + (size_t)l * 65536;

  const int sm = tid >> 6, sks = (tid >> 4) & 3, srr = tid & 15;

  auto stage = [&](int buf, int kt) {
    gl16(Az + (size_t)(16 * sm + srr) * 256 + kt + sks * 8,
         &lA[buf][(tid & ~63) * 8]);
#pragma unroll
    for (int rd = 0; rd < 2; ++rd) {
      const int nb = sm + rd * 8;
      gl16(Wz + (size_t)(nb * 16 + srr) * 256 + kt + sks * 8,
           &lB[buf][rd * 4096 + (tid & ~63) * 8]);
    }
  };

  f32x4 acc[4][4];
#pragma unroll
  for (int mi = 0; mi < 4; ++mi)
#pragma unroll
    for (int ni = 0; ni < 4; ++ni) acc[mi][ni] = (f32x4){0.f, 0.f, 0.f, 0.f};

  stage(0, 0);
  asm volatile("s_waitcnt vmcnt(0)" ::: "memory");
  __syncthreads();
  int cur = 0;
  for (int t = 0; t < 8; ++t) {
    if (t + 1 < 8) stage(cur ^ 1, (t + 1) << 5);
    bf16x8 af[4], bfr[4];
#pragma unroll
    for (int mi = 0; mi < 4; ++mi)
      af[mi] = *(const bf16x8*)&lA[cur][((wr * 4 + mi) * 64 + lane) * 8];
#pragma unroll
    for (int ni = 0; ni < 4; ++ni)
      bfr[ni] = *(const bf16x8*)&lB[cur][((wc * 4 + ni) * 64 + lane) * 8];
#pragma unroll
    for (int mi = 0; mi < 4; ++mi)
#pragma unroll
      for (int ni = 0; ni < 4; ++ni)
        acc[mi][ni] = __builtin_amdgcn_mfma_f32_16x16x32_bf16(
            af[mi], bfr[ni], acc[mi][ni], 0, 0, 0);
    asm volatile("s_waitcnt vmcnt(0)" ::: "memory");
    __syncthreads();
    cur ^= 1;
  }

  const int r_in = (lane >> 4) * 4;
  const int c_in = lane & 15;
#pragma unroll
  for (int ni = 0; ni < 4; ++ni) {
    const int cg = wc * 64 + ni * 16 + c_in;
    const float bs = bias[l * 256 + cg] + pe[l * 256 + cg];
#pragma unroll
    for (int mi = 0; mi < 4; ++mi) {
#pragma unroll
      for (int rg = 0; rg < 4; ++rg) {
        const size_t bg = b0 + wr * 64 + mi * 16 + r_in + rg;  // batch index
        y32[bg * 16384 + l * 256 + cg] = acc[mi][ni][rg] + bs;
      }
    }
  }
}

// ==== FULL LAYER: qkv+attn+Wo+LN1+ff1+ff2+LN2, one block per batch elem ====
// LAST=1: skip y32 write, emit pooled[b] (block-local column mean) instead.
template <int LAST>
__global__ __launch_bounds__(256, 2) void layer_k(
    float* __restrict__ y32,
    const ushort_t* __restrict__ Wq, const float* __restrict__ bqkv,
    const ushort_t* __restrict__ Wo, const float* __restrict__ bo,
    const float* __restrict__ ln1g, const float* __restrict__ ln1b,
    const ushort_t* __restrict__ Wf1, const float* __restrict__ bf1,
    const ushort_t* __restrict__ Wf2, const float* __restrict__ bf2,
    const float* __restrict__ ln2g, const float* __restrict__ ln2b,
    float* __restrict__ pool) {
  __shared__ ushort_t yF[16384];     // 32 KB: y / O / y1 frag tile
  __shared__ ushort_t sc[18432];     // 36.9 KB: attn per-wave bufs | zF alias
  __shared__ float red[4][2][64];    // 2 KB
  const int b = blockIdx.x;
  const int tid = threadIdx.x, lane = tid & 63, w = tid >> 6;
  const int li = lane & 15, g = lane >> 4;
  const size_t row0 = (size_t)b * 64;
  const float scale = 0.17677669529663687f;
  ushort_t* bufw = sc + w * 2304;          // Q/K [64][36] then PT [32][72]
  ushort_t* vtw  = sc + 9216 + w * 2304;   // V^T [32][72]
  ushort_t* zF   = sc;                     // ff1 quarter tile (FF phase)

  // ---- stage: y32 -> bf16 frag tile (cvt_pk) ----
#pragma unroll
  for (int j = 0; j < 8; ++j) {
    const int u = j * 256 + tid;
    const int row = u & 63, ks = u >> 6;    // ks in 0..31
    const float* src = y32 + (row0 + row) * 256 + ks * 8;
    const float4 a = *(const float4*)src;
    const float4 c = *(const float4*)(src + 4);
    uint4 v;
    v.x = pk2bf(a.x, a.y);
    v.y = pk2bf(a.z, a.w);
    v.z = pk2bf(c.x, c.y);
    v.w = pk2bf(c.z, c.w);
    *(uint4*)&yF[(((row >> 4) * 32 + ks) * 16 + (row & 15)) * 8] = v;
  }
  __syncthreads();

  // ---- attention phase (4 waves x 2 heads) ----
  f32x4 oa2[2][4][2];
#pragma unroll
  for (int hi = 0; hi < 2; ++hi) {
    const int h = w * 2 + hi, hoff = h * 32;

    f32x4 acc[3][2][4];
#pragma unroll
    for (int m = 0; m < 3; ++m)
#pragma unroll
      for (int n = 0; n < 2; ++n)
#pragma unroll
        for (int mi = 0; mi < 4; ++mi) acc[m][n][mi] = (f32x4){0.f, 0.f, 0.f, 0.f};
    __builtin_amdgcn_s_setprio(1);
#pragma unroll
    for (int kt = 0; kt < 8; ++kt) {
      bf16x8 af[4];
#pragma unroll
      for (int mi = 0; mi < 4; ++mi)
        af[mi] = *(const bf16x8*)&yF[((mi * 32 + kt * 4 + g) * 16 + li) * 8];
      bf16x8 bw[3][2];
#pragma unroll
      for (int m = 0; m < 3; ++m)
#pragma unroll
        for (int n = 0; n < 2; ++n)
          bw[m][n] = *(const bf16x8*)(Wq +
              (size_t)(((m * 16 + 2 * h + n) * 32 + kt * 4 + g) * 16 + li) * 8);
#pragma unroll
      for (int m = 0; m < 3; ++m)
#pragma unroll
        for (int n = 0; n < 2; ++n)
#pragma unroll
          for (int mi = 0; mi < 4; ++mi)
            acc[m][n][mi] = __builtin_amdgcn_mfma_f32_16x16x32_bf16(
                af[mi], bw[m][n], acc[m][n][mi], 0, 0, 0);
    }
    __builtin_amdgcn_s_setprio(0);
    float bs[3][2];
#pragma unroll
    for (int m = 0; m < 3; ++m)
#pragma unroll
      for (int n = 0; n < 2; ++n) bs[m][n] = bqkv[m * 256 + hoff + 16 * n + li];

    // Q -> bufw [64][36], read qb
#pragma unroll
    for (int n = 0; n < 2; ++n)
#pragma unroll
      for (int mi = 0; mi < 4; ++mi) {
        const unsigned p0 = pk2bf(acc[0][n][mi][0] + bs[0][n],
                                  acc[0][n][mi][1] + bs[0][n]);
        const unsigned p1 = pk2bf(acc[0][n][mi][2] + bs[0][n],
                                  acc[0][n][mi][3] + bs[0][n]);
        const int base = (16 * mi + 4 * g) * 36 + 16 * n + li;
        bufw[base]       = (ushort_t)p0;
        bufw[base + 36]  = (ushort_t)(p0 >> 16);
        bufw[base + 72]  = (ushort_t)p1;
        bufw[base + 108] = (ushort_t)(p1 >> 16);
      }
    bf16x8 qb[4];
#pragma unroll
    for (int ni = 0; ni < 4; ++ni)
      qb[ni] = *(const bf16x8*)&bufw[(16 * ni + li) * 36 + g * 8];

    // K -> bufw (overwrite), read ka
#pragma unroll
    for (int n = 0; n < 2; ++n)
#pragma unroll
      for (int mi = 0; mi < 4; ++mi) {
        const unsigned p0 = pk2bf(acc[1][n][mi][0] + bs[1][n],
                                  acc[1][n][mi][1] + bs[1][n]);
        const unsigned p1 = pk2bf(acc[1][n][mi][2] + bs[1][n],
                                  acc[1][n][mi][3] + bs[1][n]);
        const int base = (16 * mi + 4 * g) * 36 + 16 * n + li;
        bufw[base]       = (ushort_t)p0;
        bufw[base + 36]  = (ushort_t)(p0 >> 16);
        bufw[base + 72]  = (ushort_t)p1;
        bufw[base + 108] = (ushort_t)(p1 >> 16);
      }
    bf16x8 ka[4];
#pragma unroll
    for (int mi = 0; mi < 4; ++mi)
      ka[mi] = *(const bf16x8*)&bufw[(16 * mi + li) * 36 + g * 8];

    // V^T -> vtw [32][72] (contiguous in r -> uint2 store), read vb
#pragma unroll
    for (int n = 0; n < 2; ++n)
#pragma unroll
      for (int mi = 0; mi < 4; ++mi) {
        const unsigned p0 = pk2bf(acc[2][n][mi][0] + bs[2][n],
                                  acc[2][n][mi][1] + bs[2][n]);
        const unsigned p1 = pk2bf(acc[2][n][mi][2] + bs[2][n],
                                  acc[2][n][mi][3] + bs[2][n]);
        *(uint2*)&vtw[(16 * n + li) * 72 + 16 * mi + 4 * g] = make_uint2(p0, p1);
      }
    bf16x8 vb[2][2];
#pragma unroll
    for (int ks = 0; ks < 2; ++ks)
#pragma unroll
      for (int n2 = 0; n2 < 2; ++n2)
        vb[ks][n2] = *(const bf16x8*)&vtw[(16 * n2 + li) * 72 + ks * 32 + g * 8];

#pragma unroll
    for (int mi = 0; mi < 4; ++mi)
#pragma unroll
      for (int n2 = 0; n2 < 2; ++n2) oa2[hi][mi][n2] = (f32x4){0.f, 0.f, 0.f, 0.f};

#pragma unroll
    for (int half = 0; half < 2; ++half) {
      f32x4 s[4][2];
      __builtin_amdgcn_s_setprio(1);
#pragma unroll
      for (int mi = 0; mi < 4; ++mi)
#pragma unroll
        for (int nn = 0; nn < 2; ++nn)
          s[mi][nn] = __builtin_amdgcn_mfma_f32_16x16x32_bf16(
              ka[mi], qb[2 * half + nn], (f32x4){0.f, 0.f, 0.f, 0.f}, 0, 0, 0);
      __builtin_amdgcn_s_setprio(0);

#pragma unroll
      for (int nn = 0; nn < 2; ++nn) {
        float mx = -3.4e38f;
#pragma unroll
        for (int mi = 0; mi < 4; ++mi)
#pragma unroll
          for (int r = 0; r < 4; ++r) {
            s[mi][nn][r] *= scale;
            mx = fmaxf(mx, s[mi][nn][r]);
          }
        mx = fmaxf(mx, __shfl_xor(mx, 16, 64));
        mx = fmaxf(mx, __shfl_xor(mx, 32, 64));
        float sum = 0.f;
#pragma unroll
        for (int mi = 0; mi < 4; ++mi)
#pragma unroll
          for (int r = 0; r < 4; ++r) {
            const float e = expf(s[mi][nn][r] - mx);
            s[mi][nn][r] = e;
            sum += e;
          }
        sum += __shfl_xor(sum, 16, 64);
        sum += __shfl_xor(sum, 32, 64);
        const float inv = 1.f / sum;
        const int qrow = 16 * nn + li;
#pragma unroll
        for (int mi = 0; mi < 4; ++mi) {
          const unsigned lo = pk2bf(s[mi][nn][0] * inv, s[mi][nn][1] * inv);
          const unsigned hi2 = pk2bf(s[mi][nn][2] * inv, s[mi][nn][3] * inv);
          *(uint2*)&bufw[qrow * 72 + 16 * mi + 4 * g] = make_uint2(lo, hi2);
        }
      }

      __builtin_amdgcn_s_setprio(1);
#pragma unroll
      for (int ks = 0; ks < 2; ++ks) {
        bf16x8 pa[2];
#pragma unroll
        for (int m2 = 0; m2 < 2; ++m2)
          pa[m2] = *(const bf16x8*)&bufw[(16 * m2 + li) * 72 + ks * 32 + g * 8];
#pragma unroll
        for (int m2 = 0; m2 < 2; ++m2)
#pragma unroll
          for (int n2 = 0; n2 < 2; ++n2)
            oa2[hi][2 * half + m2][n2] = __builtin_amdgcn_mfma_f32_16x16x32_bf16(
                pa[m2], vb[ks][n2], oa2[hi][2 * half + m2][n2], 0, 0, 0);
      }
      __builtin_amdgcn_s_setprio(0);
    }
  }

  __syncthreads();  // all yF reads + sc use complete
  // O -> yF fragment order
#pragma unroll
  for (int hi = 0; hi < 2; ++hi) {
    const int hoff = (2 * w + hi) * 32;
#pragma unroll
    for (int mi = 0; mi < 4; ++mi)
#pragma unroll
      for (int n2 = 0; n2 < 2; ++n2) {
        const unsigned p0 = pk2bf(oa2[hi][mi][n2][0], oa2[hi][mi][n2][1]);
        const unsigned p1 = pk2bf(oa2[hi][mi][n2][2], oa2[hi][mi][n2][3]);
        const int col = hoff + 16 * n2 + li;
        const int base = ((mi * 32 + (col >> 3)) * 16 + 4 * g) * 8 + (col & 7);
        yF[base]      = (ushort_t)p0;
        yF[base + 8]  = (ushort_t)(p0 >> 16);
        yF[base + 16] = (ushort_t)p1;
        yF[base + 24] = (ushort_t)(p1 >> 16);
      }
  }
  __syncthreads();

  // ---- Wo GEMM: wave w -> cols [64w, 64w+64), K=256 ----
  f32x4 acc[4][4];
#pragma unroll
  for (int mi = 0; mi < 4; ++mi)
#pragma unroll
    for (int ni = 0; ni < 4; ++ni) acc[mi][ni] = (f32x4){0.f, 0.f, 0.f, 0.f};
  __builtin_amdgcn_s_setprio(1);
#pragma unroll
  for (int kt = 0; kt < 8; ++kt) {
    bf16x8 af[4], bfr[4];
#pragma unroll
    for (int mi = 0; mi < 4; ++mi)
      af[mi] = *(const bf16x8*)&yF[((mi * 32 + kt * 4 + g) * 16 + li) * 8];
#pragma unroll
    for (int ni = 0; ni < 4; ++ni)
      bfr[ni] = *(const bf16x8*)(Wo +
          (size_t)(((4 * w + ni) * 32 + kt * 4 + g) * 16 + li) * 8);
#pragma unroll
    for (int mi = 0; mi < 4; ++mi)
#pragma unroll
      for (int ni = 0; ni < 4; ++ni)
        acc[mi][ni] = __builtin_amdgcn_mfma_f32_16x16x32_bf16(
            af[mi], bfr[ni], acc[mi][ni], 0, 0, 0);
  }
  __builtin_amdgcn_s_setprio(0);

  // ---- LN1: residual from y32, y1 -> registers (fp32) ----
  const int r_in = (lane >> 4) * 4;
  const int c_in = lane & 15;
  float y1r[4][4][4];
#pragma unroll
  for (int mi = 0; mi < 4; ++mi) {
#pragma unroll
    for (int rg = 0; rg < 4; ++rg) {
      const int row_l = 16 * mi + r_in + rg;
      float s1 = 0.f, s2 = 0.f;
#pragma unroll
      for (int ni = 0; ni < 4; ++ni) {
        const int cg = 64 * w + 16 * ni + c_in;
        const float zv = acc[mi][ni][rg] + bo[cg] + y32[(row0 + row_l) * 256 + cg];
        acc[mi][ni][rg] = zv;
        s1 += zv;
        s2 += zv * zv;
      }
#pragma unroll
      for (int off = 1; off <= 8; off <<= 1) {
        s1 += __shfl_xor(s1, off, 64);
        s2 += __shfl_xor(s2, off, 64);
      }
      if (c_in == 0) {
        red[w][0][row_l] = s1;
        red[w][1][row_l] = s2;
      }
    }
  }
  __syncthreads();  // also: all Wo yF reads complete
#pragma unroll
  for (int mi = 0; mi < 4; ++mi) {
#pragma unroll
    for (int rg = 0; rg < 4; ++rg) {
      const int row_l = 16 * mi + r_in + rg;
      const float S1 = red[0][0][row_l] + red[1][0][row_l] + red[2][0][row_l] + red[3][0][row_l];
      const float S2 = red[0][1][row_l] + red[1][1][row_l] + red[2][1][row_l] + red[3][1][row_l];
      const float m = S1 * (1.f / 256.f);
      const float var = S2 * (1.f / 256.f) - m * m;
      const float rs = rsqrtf(var + 1e-5f);
      float tv[4];
#pragma unroll
      for (int ni = 0; ni < 4; ++ni) {
        const int cg = 64 * w + 16 * ni + c_in;
        tv[ni] = (acc[mi][ni][rg] - m) * rs * ln1g[cg] + ln1b[cg];
        y1r[mi][ni][rg] = tv[ni];
      }
      const unsigned p0 = pk2bf(tv[0], tv[1]);
      const unsigned p1 = pk2bf(tv[2], tv[3]);
#pragma unroll
      for (int ni = 0; ni < 4; ++ni) {
        const int cg = 64 * w + 16 * ni + c_in;
        const unsigned pk = (ni < 2) ? p0 : p1;
        const ushort_t hv = (ni & 1) ? (ushort_t)(pk >> 16) : (ushort_t)pk;
        yF[((mi * 32 + (cg >> 3)) * 16 + (row_l & 15)) * 8 + (cg & 7)] = hv;
      }
    }
  }
  __syncthreads();

  // ---- FF phase: ff1 quarters (zF in sc) + ff2 accumulate ----
  f32x4 acc2[4][4];
#pragma unroll
  for (int mi = 0; mi < 4; ++mi)
#pragma unroll
    for (int ni = 0; ni < 4; ++ni) acc2[mi][ni] = (f32x4){0.f, 0.f, 0.f, 0.f};

#pragma unroll 1
  for (int q = 0; q < 4; ++q) {
#pragma unroll 1
    for (int p = 0; p < 2; ++p) {
      // ff1: cols [256q + 64w + 32p, +32)
      f32x4 acc1[4][2];
#pragma unroll
      for (int mi = 0; mi < 4; ++mi)
#pragma unroll
        for (int n = 0; n < 2; ++n) acc1[mi][n] = (f32x4){0.f, 0.f, 0.f, 0.f};
      __builtin_amdgcn_s_setprio(1);
#pragma unroll
      for (int kt = 0; kt < 8; ++kt) {
        bf16x8 af[4], bw[2];
#pragma unroll
        for (int mi = 0; mi < 4; ++mi)
          af[mi] = *(const bf16x8*)&yF[((mi * 32 + kt * 4 + g) * 16 + li) * 8];
#pragma unroll
        for (int n = 0; n < 2; ++n)
          bw[n] = *(const bf16x8*)(Wf1 +
              (size_t)(((16 * q + 4 * w + 2 * p + n) * 32 + kt * 4 + g) * 16 + li) * 8);
#pragma unroll
        for (int mi = 0; mi < 4; ++mi)
#pragma unroll
          for (int n = 0; n < 2; ++n)
            acc1[mi][n] = __builtin_amdgcn_mfma_f32_16x16x32_bf16(
                af[mi], bw[n], acc1[mi][n], 0, 0, 0);
      }
      __builtin_amdgcn_s_setprio(0);
      if (q && p == 0) __syncthreads();  // prior quarter's zF reads complete
      // relu+bias -> zF frag order (kk = local col in quarter)
#pragma unroll
      for (int n = 0; n < 2; ++n) {
        const int kk = 64 * w + 32 * p + 16 * n + li;
        const float bb = bf1[256 * q + kk];
#pragma unroll
        for (int mi = 0; mi < 4; ++mi) {
          const unsigned p0 = pk2bf(fmaxf(acc1[mi][n][0] + bb, 0.f),
                                    fmaxf(acc1[mi][n][1] + bb, 0.f));
          const unsigned p1 = pk2bf(fmaxf(acc1[mi][n][2] + bb, 0.f),
                                    fmaxf(acc1[mi][n][3] + bb, 0.f));
          const int base = ((mi * 32 + (kk >> 3)) * 16 + 4 * g) * 8 + (kk & 7);
          zF[base]      = (ushort_t)p0;
          zF[base + 8]  = (ushort_t)(p0 >> 16);
          zF[base + 16] = (ushort_t)p1;
          zF[base + 24] = (ushort_t)(p1 >> 16);
        }
      }
    }
    __syncthreads();
    // ff2 partial: K-slice [256q, +256), wave w -> out cols [64w, 64w+64)
    __builtin_amdgcn_s_setprio(1);
#pragma unroll
    for (int kt = 0; kt < 8; ++kt) {
      bf16x8 af2[4], bw2[4];
#pragma unroll
      for (int mi = 0; mi < 4; ++mi)
        af2[mi] = *(const bf16x8*)&zF[((mi * 32 + kt * 4 + g) * 16 + li) * 8];
#pragma unroll
      for (int ni = 0; ni < 4; ++ni)
        bw2[ni] = *(const bf16x8*)(Wf2 +
            (size_t)(((4 * w + ni) * 128 + 32 * q + kt * 4 + g) * 16 + li) * 8);
#pragma unroll
      for (int mi = 0; mi < 4; ++mi)
#pragma unroll
        for (int ni = 0; ni < 4; ++ni)
          acc2[mi][ni] = __builtin_amdgcn_mfma_f32_16x16x32_bf16(
              af2[mi], bw2[ni], acc2[mi][ni], 0, 0, 0);
    }
    __builtin_amdgcn_s_setprio(0);
  }

  // ---- LN2: residual = y1r (fp32 regs); write y32 or pooled ----
#pragma unroll
  for (int mi = 0; mi < 4; ++mi) {
#pragma unroll
    for (int rg = 0; rg < 4; ++rg) {
      const int row_l = 16 * mi + r_in + rg;
      float s1 = 0.f, s2 = 0.f;
#pragma unroll
      for (int ni = 0; ni < 4; ++ni) {
        const int cg = 64 * w + 16 * ni + c_in;
        const float zv = acc2[mi][ni][rg] + bf2[cg] + y1r[mi][ni][rg];
        acc2[mi][ni][rg] = zv;
        s1 += zv;
        s2 += zv * zv;
      }
#pragma unroll
      for (int off = 1; off <= 8; off <<= 1) {
        s1 += __shfl_xor(s1, off, 64);
        s2 += __shfl_xor(s2, off, 64);
      }
      if (c_in == 0) {
        red[w][0][row_l] = s1;
        red[w][1][row_l] = s2;
      }
    }
  }
  __syncthreads();
  float colsum[4] = {0.f, 0.f, 0.f, 0.f};
#pragma unroll
  for (int mi = 0; mi < 4; ++mi) {
#pragma unroll
    for (int rg = 0; rg < 4; ++rg) {
      const int row_l = 16 * mi + r_in + rg;
      const float S1 = red[0][0][row_l] + red[1][0][row_l] + red[2][0][row_l] + red[3][0][row_l];
      const float S2 = red[0][1][row_l] + red[1][1][row_l] + red[2][1][row_l] + red[3][1][row_l];
      const float m = S1 * (1.f / 256.f);
      const float var = S2 * (1.f / 256.f) - m * m;
      const float rs = rsqrtf(var + 1e-5f);
#pragma unroll
      for (int ni = 0; ni < 4; ++ni) {
        const int cg = 64 * w + 16 * ni + c_in;
        const float v = (acc2[mi][ni][rg] - m) * rs * ln2g[cg] + ln2b[cg];
        if constexpr (LAST) {
          colsum[ni] += v;
        } else {
          y32[(row0 + row_l) * 256 + cg] = v;
        }
      }
    }
  }
  if constexpr (LAST) {
    // sum across the 4 row-groups (lanes c_in+16g) -> full 64-row column sum
#pragma unroll
    for (int ni = 0; ni < 4; ++ni) {
      float s = colsum[ni];
      s += __shfl_xor(s, 16, 64);
      s += __shfl_xor(s, 32, 64);
      if (g == 0) pool[(size_t)b * 256 + 64 * w + 16 * ni + c_in] = s * (1.f / 64.f);
    }
  }
}

// ---------------- fp32 head GEMM (64-row tile, relu) ----------------
__global__ __launch_bounds__(256) void headgemm_k(
    const float* __restrict__ A, const float* __restrict__ Wt,
    const float* __restrict__ bias, float* __restrict__ out) {
  const int tid = threadIdx.x;
  const int tx = tid & 63, ty = tid >> 6;
  const int cfull = tx * 4;
  const size_t b0 = (size_t)blockIdx.x * 64;

  __shared__ float At[256][68];

  float4 acc[16];
#pragma unroll
  for (int r = 0; r < 16; ++r) acc[r] = make_float4(0.f, 0.f, 0.f, 0.f);
  const int r0 = ty * 16;

  {
    const int rr = tid >> 6;
    const int k4 = (tid & 63) * 4;
#pragma unroll
    for (int p = 0; p < 16; ++p) {
      const int r = p * 4 + rr;
      const float4 v = *(const float4*)(A + (b0 + r) * 256 + k4);
      At[k4 + 0][r] = v.x;
      At[k4 + 1][r] = v.y;
      At[k4 + 2][r] = v.z;
      At[k4 + 3][r] = v.w;
    }
  }
  __syncthreads();
  const float* wp = Wt + cfull;
#pragma unroll 2
  for (int k = 0; k < 256; ++k) {
    const float4 w = *(const float4*)wp;
    wp += 256;
    const float4* ar = (const float4*)(&At[k][r0]);
    const float4 a0 = ar[0], a1 = ar[1], a2 = ar[2], a3 = ar[3];
    const float av[16] = {a0.x, a0.y, a0.z, a0.w, a1.x, a1.y, a1.z, a1.w,
                          a2.x, a2.y, a2.z, a2.w, a3.x, a3.y, a3.z, a3.w};
#pragma unroll
    for (int r = 0; r < 16; ++r) {
      acc[r].x = fmaf(av[r], w.x, acc[r].x);
      acc[r].y = fmaf(av[r], w.y, acc[r].y);
      acc[r].z = fmaf(av[r], w.z, acc[r].z);
      acc[r].w = fmaf(av[r], w.w, acc[r].w);
    }
  }
  const float4 bb = *(const float4*)(bias + cfull);
#pragma unroll
  for (int r = 0; r < 16; ++r) {
    const size_t row = b0 + r0 + r;
    float4 o;
    o.x = fmaxf(acc[r].x + bb.x, 0.f);
    o.y = fmaxf(acc[r].y + bb.y, 0.f);
    o.z = fmaxf(acc[r].z + bb.z, 0.f);
    o.w = fmaxf(acc[r].w + bb.w, 0.f);
    *(float4*)(out + row * 256 + cfull) = o;
  }
}

__global__ __launch_bounds__(64) void head2_k(const float* __restrict__ hh,
                                              const float* __restrict__ W2,
                                              const float* __restrict__ b2,
                                              float* __restrict__ out) {
  const size_t b = blockIdx.x;
  const int lane = threadIdx.x;
  const float4 hv = *(const float4*)(hh + b * T_ + lane * 4);
  const float4 wv = *(const float4*)(W2 + lane * 4);
  float s = hv.x * wv.x + hv.y * wv.y + hv.z * wv.z + hv.w * wv.w;
  s = wred_sum(s);
  if (lane == 0) out[b] = s + b2[0];
}

// ---------------- launch ----------------
extern "C" void kernel_launch(void* const* d_in, const int* in_sizes, int n_in,
                              void* d_out, int out_size, void* d_ws, size_t ws_size,
                              hipStream_t stream) {
  const float* link_states = (const float*)d_in[0];
  const float* link_W1 = (const float*)d_in[1];
  const float* link_b1 = (const float*)d_in[2];
  const float* link_W2 = (const float*)d_in[3];
  const float* link_b2 = (const float*)d_in[4];
  const float* Wqkv = (const float*)d_in[5];
  const float* bqkv = (const float*)d_in[6];
  const float* Wo = (const float*)d_in[7];
  const float* bo = (const float*)d_in[8];
  const float* ln1_g = (const float*)d_in[9];
  const float* ln1_b = (const float*)d_in[10];
  const float* Wff1 = (const float*)d_in[11];
  const float* bff1 = (const float*)d_in[12];
  const float* Wff2 = (const float*)d_in[13];
  const float* bff2 = (const float*)d_in[14];
  const float* ln2_g = (const float*)d_in[15];
  const float* ln2_b = (const float*)d_in[16];
  const float* head_W1 = (const float*)d_in[17];
  const float* head_b1 = (const float*)d_in[18];
  const float* head_W2 = (const float*)d_in[19];
  const float* head_b2 = (const float*)d_in[20];

  char* base = (char*)d_ws;
  size_t off = 0;
  auto alloc = [&](size_t bytes) -> char* {
    char* p = base + off;
    off = (off + bytes + 255) & ~(size_t)255;
    return p;
  };

  // ---- fixed region (~29.4 MB) ----
  ushort_t* Wqkv16 = (ushort_t*)alloc((size_t)NL_ * 768 * 256 * 2);
  ushort_t* Wo16   = (ushort_t*)alloc((size_t)NL_ * 256 * 256 * 2);
  ushort_t* Wff116 = (ushort_t*)alloc((size_t)NL_ * 1024 * 256 * 2);
  ushort_t* Wff216 = (ushort_t*)alloc((size_t)NL_ * 256 * 1024 * 2);
  ushort_t* W2T16  = (ushort_t*)alloc((size_t)L_ * 256 * 256 * 2);
  float* pe     = (float*)alloc((size_t)L_ * T_ * 4);
  float* xn     = (float*)alloc((size_t)B_ * L_ * DIN_ * 4);
  float* pooled = (float*)alloc((size_t)B_ * T_ * 4);
  float* hh     = (float*)alloc((size_t)B_ * T_ * 4);

  // ---- chunked region: 98,304 B per batch element (y32 + hbuf) ----
  const size_t fixed_end = off;
  const size_t availB = (ws_size > fixed_end + 65536) ? (ws_size - fixed_end - 65536) : 0;
  int NC = 1;
  while (NC < 32 && (size_t)(B_ / NC) * 98304ull > availB) NC <<= 1;
  const int Bc = B_ / NC;

  float*    y32  = (float*)alloc((size_t)Bc * L_ * T_ * 4);
  ushort_t* hbuf = (ushort_t*)alloc((size_t)Bc * L_ * T_ * 2);  // [l][b][256]

  // ---- prep: all weight transforms + pe in ONE launch ----
  prep_k<<<28704, 256, 0, stream>>>(Wqkv, Wqkv16, Wo, Wo16, Wff1, Wff116,
                                    Wff2, Wff216, link_W2, W2T16, pe);
  normalize_k<<<B_ / 4, 256, 0, stream>>>(link_states, xn);

  for (int c = 0; c < NC; ++c) {
    const size_t bs = (size_t)c * Bc;

    // ---- link MLP (h stored l-major for contiguous linkgemm A-tiles) ----
    link1_k<<<(Bc * L_) / 16, 256, 0, stream>>>(xn + bs * L_ * DIN_, link_W1,
                                                link_b1, hbuf, Bc);
    linkgemm_k<<<dim3(Bc / 128, 1, L_), 512, 0, stream>>>(
        hbuf, W2T16, link_b2, pe, y32, Bc);

    // ---- 4 fused layers (last fuses pooling, skips y32 write) ----
    for (int l = 0; l < NL_ - 1; ++l) {
      layer_k<0><<<dim3(Bc, 1, 1), 256, 0, stream>>>(
          y32,
          Wqkv16 + (size_t)l * 768 * 256, bqkv + l * 768,
          Wo16 + (size_t)l * 256 * 256, bo + l * 256,
          ln1_g + l * 256, ln1_b + l * 256,
          Wff116 + (size_t)l * 1024 * 256, bff1 + l * 1024,
          Wff216 + (size_t)l * 256 * 1024, bff2 + l * 256,
          ln2_g + l * 256, ln2_b + l * 256, nullptr);
    }
    {
      const int l = NL_ - 1;
      layer_k<1><<<dim3(Bc, 1, 1), 256, 0, stream>>>(
          y32,
          Wqkv16 + (size_t)l * 768 * 256, bqkv + l * 768,
          Wo16 + (size_t)l * 256 * 256, bo + l * 256,
          ln1_g + l * 256, ln1_b + l * 256,
          Wff116 + (size_t)l * 1024 * 256, bff1 + l * 1024,
          Wff216 + (size_t)l * 256 * 1024, bff2 + l * 256,
          ln2_g + l * 256, ln2_b + l * 256, pooled + bs * T_);
    }
  }

  // ---- head (fp32) ----
  headgemm_k<<<B_ / 64, 256, 0, stream>>>(pooled, head_W1, head_b1, hh);
  head2_k<<<B_, 64, 0, stream>>>(hh, head_W2, head_b2, (float*)d_out);
}